// Round 1
// baseline (564.080 us; speedup 1.0000x reference)
//
#include <hip/hip_runtime.h>

#define B_SZ 4096
#define F_SZ 24
#define V_SZ 1000
#define D_SZ 32
#define RED  8
#define FD   768      // F*D
#define COMB 1536
#define H0   1024
#define H1   512
#define EPS  1e-5f

#define BM 64
#define BN 64
#define BK 16

// ---------- K0: reorder bil_W -> Wmat[(j,l),(i,k)] with i==j blocks zeroed ----------
__global__ __launch_bounds__(256) void reorder_W(const float* __restrict__ bw,
                                                 float* __restrict__ wmat) {
    int o = blockIdx.x * 256 + threadIdx.x;
    if (o >= FD * FD) return;
    int jl = o / FD, ik = o - jl * FD;
    int j = jl >> 5, l = jl & 31, i = ik >> 5, k = ik & 31;
    wmat[o] = (i == j) ? 0.f : bw[((i * F_SZ + j) * D_SZ + k) * D_SZ + l];
}

// ---------- K1: embedding gather + SENet + linear term. Writes X[b]=e, X[B+b]=e*A ----------
__global__ __launch_bounds__(64) void gather_se(const int* __restrict__ x,
        const float* __restrict__ emb, const float* __restrict__ lint,
        const float* __restrict__ sw1, const float* __restrict__ sw2,
        float* __restrict__ X, float* __restrict__ lin) {
    int b = blockIdx.x;
    int t = threadIdx.x;
    __shared__ int   xi[F_SZ];
    __shared__ float e[F_SZ][D_SZ];
    __shared__ float Z[F_SZ];
    __shared__ float r1[RED];
    __shared__ float Afac[F_SZ];
    if (t < F_SZ) xi[t] = x[b * F_SZ + t];
    __syncthreads();
    for (int idx = t; idx < FD; idx += 64) {
        int f = idx >> 5, k = idx & 31;
        e[f][k] = emb[((size_t)f * V_SZ + xi[f]) * D_SZ + k];
    }
    __syncthreads();
    if (t < F_SZ) {
        float s = 0.f;
        #pragma unroll
        for (int k = 0; k < D_SZ; k++) s += e[t][k];
        Z[t] = s * (1.f / D_SZ);
    }
    __syncthreads();
    if (t < RED) {
        float s = 0.f;
        #pragma unroll
        for (int f = 0; f < F_SZ; f++) s += Z[f] * sw1[t * F_SZ + f];
        r1[t] = fmaxf(s, 0.f);
    }
    __syncthreads();
    if (t < F_SZ) {
        float s = 0.f;
        #pragma unroll
        for (int r = 0; r < RED; r++) s += r1[r] * sw2[t * RED + r];
        Afac[t] = 1.f / (1.f + expf(-s));
    }
    __syncthreads();
    for (int idx = t; idx < FD; idx += 64) {
        int f = idx >> 5, k = idx & 31;
        float v = e[f][k];
        X[(size_t)b * FD + idx] = v;
        X[(size_t)(B_SZ + b) * FD + idx] = v * Afac[f];
    }
    float lv = (t < F_SZ) ? lint[t * V_SZ + xi[t]] : 0.f;
    #pragma unroll
    for (int off = 32; off > 0; off >>= 1) lv += __shfl_down(lv, off);
    if (t == 0) lin[b] = lv;
}

// ---------- GEMM1: S = X @ Wmat   [8192,768] x [768,768] ----------
__global__ __launch_bounds__(256) void gemm_bil(const float* __restrict__ A,
        const float* __restrict__ Bm, float* __restrict__ C) {
    const int M = 2 * B_SZ, N = FD, K = FD;
    __shared__ float As[BK][BM + 4];
    __shared__ float Bs[BK][BN];
    int tid = threadIdx.x;
    int bm = blockIdx.y * BM, bn = blockIdx.x * BN;
    int tx = tid & 15, ty = tid >> 4;
    int ak = tid & 15, am = tid >> 4;
    int bcol = tid & 63, bk = tid >> 6;
    float acc[4][4] = {};
    for (int k0 = 0; k0 < K; k0 += BK) {
        #pragma unroll
        for (int i = 0; i < 4; i++)
            As[ak][am + 16 * i] = A[(size_t)(bm + am + 16 * i) * K + k0 + ak];
        #pragma unroll
        for (int i = 0; i < 4; i++)
            Bs[bk + 4 * i][bcol] = Bm[(size_t)(k0 + bk + 4 * i) * N + bn + bcol];
        __syncthreads();
        #pragma unroll
        for (int k = 0; k < BK; k++) {
            float a[4], bb[4];
            #pragma unroll
            for (int u = 0; u < 4; u++) a[u] = As[k][ty * 4 + u];
            #pragma unroll
            for (int v = 0; v < 4; v++) bb[v] = Bs[k][tx * 4 + v];
            #pragma unroll
            for (int u = 0; u < 4; u++)
                #pragma unroll
                for (int v = 0; v < 4; v++) acc[u][v] += a[u] * bb[v];
        }
        __syncthreads();
    }
    #pragma unroll
    for (int u = 0; u < 4; u++)
        #pragma unroll
        for (int v = 0; v < 4; v++)
            C[(size_t)(bm + ty * 4 + u) * N + bn + tx * 4 + v] = acc[u][v];
}

// ---------- GEMM0: h0 = combined @ w0 + b0, combined fused as X*S ----------
__global__ __launch_bounds__(256) void gemm_mlp0(const float* __restrict__ X,
        const float* __restrict__ S, const float* __restrict__ Bm,
        const float* __restrict__ bias, float* __restrict__ C) {
    const int N = H0, K = COMB;
    __shared__ float As[BK][BM + 4];
    __shared__ float Bs[BK][BN];
    int tid = threadIdx.x;
    int bm = blockIdx.y * BM, bn = blockIdx.x * BN;
    int tx = tid & 15, ty = tid >> 4;
    int ak = tid & 15, am = tid >> 4;
    int bcol = tid & 63, bk = tid >> 6;
    float acc[4][4] = {};
    for (int k0 = 0; k0 < K; k0 += BK) {
        int c = k0 + ak;
        int cc = (c < FD) ? c : c - FD;
        int rbase = (c < FD) ? 0 : B_SZ;
        #pragma unroll
        for (int i = 0; i < 4; i++) {
            size_t off = (size_t)(rbase + bm + am + 16 * i) * FD + cc;
            As[ak][am + 16 * i] = X[off] * S[off];
        }
        #pragma unroll
        for (int i = 0; i < 4; i++)
            Bs[bk + 4 * i][bcol] = Bm[(size_t)(k0 + bk + 4 * i) * N + bn + bcol];
        __syncthreads();
        #pragma unroll
        for (int k = 0; k < BK; k++) {
            float a[4], bb[4];
            #pragma unroll
            for (int u = 0; u < 4; u++) a[u] = As[k][ty * 4 + u];
            #pragma unroll
            for (int v = 0; v < 4; v++) bb[v] = Bs[k][tx * 4 + v];
            #pragma unroll
            for (int u = 0; u < 4; u++)
                #pragma unroll
                for (int v = 0; v < 4; v++) acc[u][v] += a[u] * bb[v];
        }
        __syncthreads();
    }
    #pragma unroll
    for (int u = 0; u < 4; u++)
        #pragma unroll
        for (int v = 0; v < 4; v++)
            C[(size_t)(bm + ty * 4 + u) * N + bn + tx * 4 + v] =
                acc[u][v] + bias[bn + tx * 4 + v];
}

// ---------- GEMM2: h1 = relu(bn(h0)) @ w1 + b1 ----------
__global__ __launch_bounds__(256) void gemm_mlp1(const float* __restrict__ Hin,
        const float* __restrict__ scale, const float* __restrict__ shift,
        const float* __restrict__ Bm, const float* __restrict__ bias,
        float* __restrict__ C) {
    const int N = H1, K = H0;
    __shared__ float As[BK][BM + 4];
    __shared__ float Bs[BK][BN];
    int tid = threadIdx.x;
    int bm = blockIdx.y * BM, bn = blockIdx.x * BN;
    int tx = tid & 15, ty = tid >> 4;
    int ak = tid & 15, am = tid >> 4;
    int bcol = tid & 63, bk = tid >> 6;
    float acc[4][4] = {};
    for (int k0 = 0; k0 < K; k0 += BK) {
        int c = k0 + ak;
        float sc = scale[c], sh = shift[c];
        #pragma unroll
        for (int i = 0; i < 4; i++) {
            float v = Hin[(size_t)(bm + am + 16 * i) * K + c];
            As[ak][am + 16 * i] = fmaxf(v * sc + sh, 0.f);
        }
        #pragma unroll
        for (int i = 0; i < 4; i++)
            Bs[bk + 4 * i][bcol] = Bm[(size_t)(k0 + bk + 4 * i) * N + bn + bcol];
        __syncthreads();
        #pragma unroll
        for (int k = 0; k < BK; k++) {
            float a[4], bb[4];
            #pragma unroll
            for (int u = 0; u < 4; u++) a[u] = As[k][ty * 4 + u];
            #pragma unroll
            for (int v = 0; v < 4; v++) bb[v] = Bs[k][tx * 4 + v];
            #pragma unroll
            for (int u = 0; u < 4; u++)
                #pragma unroll
                for (int v = 0; v < 4; v++) acc[u][v] += a[u] * bb[v];
        }
        __syncthreads();
    }
    #pragma unroll
    for (int u = 0; u < 4; u++)
        #pragma unroll
        for (int v = 0; v < 4; v++)
            C[(size_t)(bm + ty * 4 + u) * N + bn + tx * 4 + v] =
                acc[u][v] + bias[bn + tx * 4 + v];
}

// ---------- BN stats: block-partial sums + device atomics ----------
__global__ __launch_bounds__(256) void bn_stats(const float* __restrict__ H, int N,
        float* __restrict__ sum, float* __restrict__ sumsq) {
    int col = blockIdx.x * 256 + threadIdx.x;
    int r0 = blockIdx.y * 256;
    float s = 0.f, ss = 0.f;
    for (int r = 0; r < 256; r++) {
        float v = H[(size_t)(r0 + r) * N + col];
        s += v;
        ss += v * v;
    }
    atomicAdd(&sum[col], s);
    atomicAdd(&sumsq[col], ss);
}

__global__ __launch_bounds__(256) void bn_finalize(const float* __restrict__ sum,
        const float* __restrict__ sumsq, const float* __restrict__ g,
        const float* __restrict__ be, int N,
        float* __restrict__ scale, float* __restrict__ shift) {
    int c = blockIdx.x * 256 + threadIdx.x;
    if (c >= N) return;
    float m = sum[c] * (1.f / B_SZ);
    float var = sumsq[c] * (1.f / B_SZ) - m * m;
    float rstd = rsqrtf(var + EPS);
    float sc = g[c] * rstd;
    scale[c] = sc;
    shift[c] = be[c] - m * sc;
}

// ---------- Final: out = sigmoid(lin + bias + relu(bn(h1)) @ w2 + b2) ----------
__global__ __launch_bounds__(64) void final_k(const float* __restrict__ h1,
        const float* __restrict__ scale1, const float* __restrict__ shift1,
        const float* __restrict__ w2, const float* __restrict__ b2,
        const float* __restrict__ lin, const float* __restrict__ bias,
        float* __restrict__ out) {
    int b = blockIdx.x;
    int t = threadIdx.x;
    float acc = 0.f;
    for (int c = t; c < H1; c += 64) {
        float v = h1[(size_t)b * H1 + c] * scale1[c] + shift1[c];
        acc += fmaxf(v, 0.f) * w2[c];
    }
    #pragma unroll
    for (int off = 32; off > 0; off >>= 1) acc += __shfl_down(acc, off);
    if (t == 0) {
        float logit = lin[b] + bias[0] + acc + b2[0];
        out[b] = 1.f / (1.f + expf(-logit));
    }
}

extern "C" void kernel_launch(void* const* d_in, const int* in_sizes, int n_in,
                              void* d_out, int out_size, void* d_ws, size_t ws_size,
                              hipStream_t stream) {
    const int*   x    = (const int*)d_in[0];
    const float* emb  = (const float*)d_in[1];
    const float* lint = (const float*)d_in[2];
    const float* bias = (const float*)d_in[3];
    const float* sw1  = (const float*)d_in[4];
    const float* sw2  = (const float*)d_in[5];
    const float* bw   = (const float*)d_in[6];
    const float* w0   = (const float*)d_in[7];
    const float* b0   = (const float*)d_in[8];
    const float* g0   = (const float*)d_in[9];
    const float* be0  = (const float*)d_in[10];
    const float* w1   = (const float*)d_in[11];
    const float* b1   = (const float*)d_in[12];
    const float* g1   = (const float*)d_in[13];
    const float* be1  = (const float*)d_in[14];
    const float* w2   = (const float*)d_in[15];
    const float* b2   = (const float*)d_in[16];
    float* out = (float*)d_out;

    float* ws   = (float*)d_ws;
    float* X    = ws;                       // [8192,768]
    float* S    = X + (size_t)2 * B_SZ * FD;       // [8192,768]
    float* Wmat = S + (size_t)2 * B_SZ * FD;       // [768,768]
    float* h0   = Wmat + (size_t)FD * FD;          // [4096,1024]
    float* h1   = h0 + (size_t)B_SZ * H0;          // [4096,512]
    float* lin  = h1 + (size_t)B_SZ * H1;          // [4096]
    float* sum0   = lin + B_SZ;             // 1024
    float* sumsq0 = sum0 + H0;              // 1024
    float* sum1   = sumsq0 + H0;            // 512
    float* sumsq1 = sum1 + H1;              // 512
    float* scale0 = sumsq1 + H1;            // 1024
    float* shift0 = scale0 + H0;            // 1024
    float* scale1 = shift0 + H0;            // 512
    float* shift1 = scale1 + H1;            // 512

    hipMemsetAsync(sum0, 0, (size_t)(2 * H0 + 2 * H1) * sizeof(float), stream);

    reorder_W<<<(FD * FD + 255) / 256, 256, 0, stream>>>(bw, Wmat);
    gather_se<<<B_SZ, 64, 0, stream>>>(x, emb, lint, sw1, sw2, X, lin);
    gemm_bil<<<dim3(FD / BN, 2 * B_SZ / BM), 256, 0, stream>>>(X, Wmat, S);
    gemm_mlp0<<<dim3(H0 / BN, B_SZ / BM), 256, 0, stream>>>(X, S, w0, b0, h0);
    bn_stats<<<dim3(H0 / 256, 16), 256, 0, stream>>>(h0, H0, sum0, sumsq0);
    bn_finalize<<<H0 / 256, 256, 0, stream>>>(sum0, sumsq0, g0, be0, H0, scale0, shift0);
    gemm_mlp1<<<dim3(H1 / BN, B_SZ / BM), 256, 0, stream>>>(h0, scale0, shift0, w1, b1, h1);
    bn_stats<<<dim3(H1 / 256, 16), 256, 0, stream>>>(h1, H1, sum1, sumsq1);
    bn_finalize<<<(H1 + 255) / 256, 256, 0, stream>>>(sum1, sumsq1, g1, be1, H1, scale1, shift1);
    final_k<<<B_SZ, 64, 0, stream>>>(h1, scale1, shift1, w2, b2, lin, bias, out);
}

// Round 2
// 250.736 us; speedup vs baseline: 2.2497x; 2.2497x over previous
//
#include <hip/hip_runtime.h>

#define B_SZ 4096
#define F_SZ 24
#define V_SZ 1000
#define D_SZ 32
#define RED  8
#define FD   768      // F*D
#define COMB 1536
#define H0   1024
#define H1   512
#define EPS  1e-5f

typedef __bf16 bf16x8 __attribute__((ext_vector_type(8)));
typedef float  f32x4  __attribute__((ext_vector_type(4)));
typedef const __attribute__((address_space(1))) unsigned int* gptr_t;
typedef       __attribute__((address_space(3))) unsigned int* lptr_t;

__device__ __forceinline__ float bf2f(unsigned short u) {
    union { unsigned int i; float f; } v; v.i = ((unsigned int)u) << 16; return v.f;
}
__device__ __forceinline__ unsigned short f2bf(float f) {
    union { float f; unsigned int i; } v; v.f = f;
    unsigned int u = v.i;
    unsigned int r = (u + 0x7FFFu + ((u >> 16) & 1u)) >> 16;
    return (unsigned short)r;
}

// ---------- K0: reorder bil_W -> Wt[(i,k)][(j,l)] bf16 (B^T layout), i==j zeroed ----------
__global__ __launch_bounds__(256) void reorder_W(const float* __restrict__ bw,
                                                 unsigned short* __restrict__ wt) {
    int o = blockIdx.x * 256 + threadIdx.x;   // o = ik*768 + jl
    if (o >= FD * FD) return;
    int ik = o / FD, jl = o - ik * FD;
    int i = ik >> 5, k = ik & 31, j = jl >> 5, l = jl & 31;
    wt[o] = (i == j) ? (unsigned short)0
                     : f2bf(bw[(((size_t)i * F_SZ + j) * D_SZ + k) * D_SZ + l]);
}

// ---------- transpose fp32 [K,N] -> bf16 [N,K] ----------
__global__ __launch_bounds__(256) void transpose_bf(const float* __restrict__ in,
        unsigned short* __restrict__ out, int K, int N) {
    __shared__ float tile[32][33];
    int tx = threadIdx.x & 31, ty = threadIdx.x >> 5;     // 32 x 8
    int n0 = blockIdx.x * 32, k0 = blockIdx.y * 32;
    #pragma unroll
    for (int r = 0; r < 32; r += 8)
        tile[ty + r][tx] = in[(size_t)(k0 + ty + r) * N + n0 + tx];
    __syncthreads();
    #pragma unroll
    for (int r = 0; r < 32; r += 8)
        out[(size_t)(n0 + ty + r) * K + k0 + tx] = f2bf(tile[tx][ty + r]);
}

// ---------- K1: embedding gather + SENet + linear term. Writes Xbf (bf16) ----------
__global__ __launch_bounds__(64) void gather_se(const int* __restrict__ x,
        const float* __restrict__ emb, const float* __restrict__ lint,
        const float* __restrict__ sw1, const float* __restrict__ sw2,
        unsigned short* __restrict__ Xbf, float* __restrict__ lin) {
    int b = blockIdx.x;
    int t = threadIdx.x;
    __shared__ int   xi[F_SZ];
    __shared__ float e[F_SZ][D_SZ];
    __shared__ float Z[F_SZ];
    __shared__ float r1[RED];
    __shared__ float Afac[F_SZ];
    if (t < F_SZ) xi[t] = x[b * F_SZ + t];
    __syncthreads();
    for (int idx = t; idx < FD; idx += 64) {
        int f = idx >> 5, k = idx & 31;
        e[f][k] = emb[((size_t)f * V_SZ + xi[f]) * D_SZ + k];
    }
    __syncthreads();
    if (t < F_SZ) {
        float s = 0.f;
        #pragma unroll
        for (int k = 0; k < D_SZ; k++) s += e[t][k];
        Z[t] = s * (1.f / D_SZ);
    }
    __syncthreads();
    if (t < RED) {
        float s = 0.f;
        #pragma unroll
        for (int f = 0; f < F_SZ; f++) s += Z[f] * sw1[t * F_SZ + f];
        r1[t] = fmaxf(s, 0.f);
    }
    __syncthreads();
    if (t < F_SZ) {
        float s = 0.f;
        #pragma unroll
        for (int r = 0; r < RED; r++) s += r1[r] * sw2[t * RED + r];
        Afac[t] = 1.f / (1.f + expf(-s));
    }
    __syncthreads();
    for (int idx = t; idx < FD; idx += 64) {
        int f = idx >> 5, k = idx & 31;
        float v = e[f][k];
        Xbf[(size_t)b * FD + idx] = f2bf(v);
        Xbf[(size_t)(B_SZ + b) * FD + idx] = f2bf(v * Afac[f]);
    }
    float lv = (t < F_SZ) ? lint[t * V_SZ + xi[t]] : 0.f;
    #pragma unroll
    for (int off = 32; off > 0; off >>= 1) lv += __shfl_down(lv, off);
    if (t == 0) lin[b] = lv;
}

// ---------- MFMA GEMM: C = A[M,K](bf16) @ Bt[N,K]^T(bf16) ----------
// 128x128 tile, BK=32, 256 thr (2x2 waves, each 4x4 of 16x16x32 MFMA).
// MODE 0: epilogue combined = Xbf .* S -> Obf (row<4096 -> cols[0,768), else +768)
// MODE 1: epilogue + bias -> Of32
template<int MODE, int K, int N>
__global__ __launch_bounds__(256) void mfma_gemm(
        const unsigned short* __restrict__ A,
        const unsigned short* __restrict__ Bt,
        const float* __restrict__ bias,
        const unsigned short* __restrict__ Xbf,
        unsigned short* __restrict__ Obf,
        float* __restrict__ Of32) {
    __shared__ unsigned short Abuf[128 * 32];
    __shared__ unsigned short Bbuf[128 * 32];
    const int tid  = threadIdx.x;
    const int lane = tid & 63, wv = tid >> 6;
    const int wm = (wv >> 1) * 64, wn = (wv & 1) * 64;
    const int fr = lane & 15, kq = lane >> 4;
    const int bm = blockIdx.y * 128, bn = blockIdx.x * 128;
    const int srow = tid >> 2;          // 0..63
    const int skc  = (tid & 3) * 8;     // 0,8,16,24

    f32x4 acc[4][4];
    #pragma unroll
    for (int i = 0; i < 4; i++)
        #pragma unroll
        for (int j = 0; j < 4; j++) {
            f32x4 z = {0.f, 0.f, 0.f, 0.f};
            acc[i][j] = z;
        }

    for (int k0 = 0; k0 < K; k0 += 32) {
        #pragma unroll
        for (int c = 0; c < 2; c++) {
            const unsigned short* ga = A  + (size_t)(bm + c * 64 + srow) * K + k0 + skc;
            const unsigned short* gb = Bt + (size_t)(bn + c * 64 + srow) * K + k0 + skc;
            char* la = (char*)Abuf + c * 4096 + wv * 1024;
            char* lb = (char*)Bbuf + c * 4096 + wv * 1024;
            __builtin_amdgcn_global_load_lds((gptr_t)ga, (lptr_t)la, 16, 0, 0);
            __builtin_amdgcn_global_load_lds((gptr_t)gb, (lptr_t)lb, 16, 0, 0);
        }
        __syncthreads();
        bf16x8 af[4], bfv[4];
        #pragma unroll
        for (int mi = 0; mi < 4; mi++)
            af[mi] = *(const bf16x8*)&Abuf[(wm + mi * 16 + fr) * 32 + kq * 8];
        #pragma unroll
        for (int ni = 0; ni < 4; ni++)
            bfv[ni] = *(const bf16x8*)&Bbuf[(wn + ni * 16 + fr) * 32 + kq * 8];
        #pragma unroll
        for (int mi = 0; mi < 4; mi++)
            #pragma unroll
            for (int ni = 0; ni < 4; ni++)
                acc[mi][ni] = __builtin_amdgcn_mfma_f32_16x16x32_bf16(
                    af[mi], bfv[ni], acc[mi][ni], 0, 0, 0);
        __syncthreads();
    }

    #pragma unroll
    for (int mi = 0; mi < 4; mi++) {
        #pragma unroll
        for (int ni = 0; ni < 4; ni++) {
            int col = bn + wn + ni * 16 + fr;
            #pragma unroll
            for (int r = 0; r < 4; r++) {
                int row = bm + wm + mi * 16 + kq * 4 + r;
                float v = acc[mi][ni][r];
                if (MODE == 0) {
                    float xv = bf2f(Xbf[(size_t)row * FD + col]);
                    float cv = xv * v;
                    size_t off = (row < B_SZ)
                        ? ((size_t)row * COMB + col)
                        : ((size_t)(row - B_SZ) * COMB + FD + col);
                    Obf[off] = f2bf(cv);
                } else {
                    Of32[(size_t)row * N + col] = v + bias[col];
                }
            }
        }
    }
}

// ---------- BN stats ----------
__global__ __launch_bounds__(256) void bn_stats(const float* __restrict__ H, int N,
        float* __restrict__ sum, float* __restrict__ sumsq) {
    int col = blockIdx.x * 256 + threadIdx.x;
    int r0 = blockIdx.y * 256;
    float s = 0.f, ss = 0.f;
    for (int r = 0; r < 256; r++) {
        float v = H[(size_t)(r0 + r) * N + col];
        s += v;
        ss += v * v;
    }
    atomicAdd(&sum[col], s);
    atomicAdd(&sumsq[col], ss);
}

__global__ __launch_bounds__(256) void bn_finalize(const float* __restrict__ sum,
        const float* __restrict__ sumsq, const float* __restrict__ g,
        const float* __restrict__ be, int N,
        float* __restrict__ scale, float* __restrict__ shift) {
    int c = blockIdx.x * 256 + threadIdx.x;
    if (c >= N) return;
    float m = sum[c] * (1.f / B_SZ);
    float var = sumsq[c] * (1.f / B_SZ) - m * m;
    float rstd = rsqrtf(var + EPS);
    float sc = g[c] * rstd;
    scale[c] = sc;
    shift[c] = be[c] - m * sc;
}

// ---------- bn_apply: A2 = bf16(relu(h0*scale+shift)) ----------
__global__ __launch_bounds__(256) void bn_apply(const float* __restrict__ h,
        const float* __restrict__ scale, const float* __restrict__ shift,
        unsigned short* __restrict__ out) {
    int idx = blockIdx.x * 256 + threadIdx.x;
    int c = idx & (H0 - 1);
    float v = h[idx] * scale[c] + shift[c];
    out[idx] = f2bf(fmaxf(v, 0.f));
}

// ---------- Final ----------
__global__ __launch_bounds__(64) void final_k(const float* __restrict__ h1,
        const float* __restrict__ scale1, const float* __restrict__ shift1,
        const float* __restrict__ w2, const float* __restrict__ b2,
        const float* __restrict__ lin, const float* __restrict__ bias,
        float* __restrict__ out) {
    int b = blockIdx.x;
    int t = threadIdx.x;
    float acc = 0.f;
    for (int c = t; c < H1; c += 64) {
        float v = h1[(size_t)b * H1 + c] * scale1[c] + shift1[c];
        acc += fmaxf(v, 0.f) * w2[c];
    }
    #pragma unroll
    for (int off = 32; off > 0; off >>= 1) acc += __shfl_down(acc, off);
    if (t == 0) {
        float logit = lin[b] + bias[0] + acc + b2[0];
        out[b] = 1.f / (1.f + expf(-logit));
    }
}

extern "C" void kernel_launch(void* const* d_in, const int* in_sizes, int n_in,
                              void* d_out, int out_size, void* d_ws, size_t ws_size,
                              hipStream_t stream) {
    const int*   x    = (const int*)d_in[0];
    const float* emb  = (const float*)d_in[1];
    const float* lint = (const float*)d_in[2];
    const float* bias = (const float*)d_in[3];
    const float* sw1  = (const float*)d_in[4];
    const float* sw2  = (const float*)d_in[5];
    const float* bw   = (const float*)d_in[6];
    const float* w0   = (const float*)d_in[7];
    const float* b0   = (const float*)d_in[8];
    const float* g0   = (const float*)d_in[9];
    const float* be0  = (const float*)d_in[10];
    const float* w1   = (const float*)d_in[11];
    const float* b1   = (const float*)d_in[12];
    const float* g1   = (const float*)d_in[13];
    const float* be1  = (const float*)d_in[14];
    const float* w2   = (const float*)d_in[15];
    const float* b2   = (const float*)d_in[16];
    float* out = (float*)d_out;

    char* p = (char*)d_ws;
    auto alloc = [&](size_t bytes) { char* r = p; p += (bytes + 255) & ~(size_t)255; return r; };

    unsigned short* Xbf  = (unsigned short*)alloc((size_t)2 * B_SZ * FD * 2);   // [8192,768]
    unsigned short* Wt   = (unsigned short*)alloc((size_t)FD * FD * 2);         // [768,768]
    unsigned short* w0t  = (unsigned short*)alloc((size_t)H0 * COMB * 2);       // [1024,1536]
    unsigned short* w1t  = (unsigned short*)alloc((size_t)H1 * H0 * 2);         // [512,1024]
    unsigned short* Cbf  = (unsigned short*)alloc((size_t)B_SZ * COMB * 2);     // [4096,1536]
    unsigned short* A2bf = (unsigned short*)alloc((size_t)B_SZ * H0 * 2);       // [4096,1024]
    float* h0  = (float*)alloc((size_t)B_SZ * H0 * 4);
    float* h1  = (float*)alloc((size_t)B_SZ * H1 * 4);
    float* lin = (float*)alloc(B_SZ * 4);
    float* sums   = (float*)alloc((2 * H0 + 2 * H1) * 4);  // sum0,sumsq0,sum1,sumsq1
    float* scale0 = (float*)alloc(H0 * 4);
    float* shift0 = (float*)alloc(H0 * 4);
    float* scale1 = (float*)alloc(H1 * 4);
    float* shift1 = (float*)alloc(H1 * 4);
    float* sum0 = sums, *sumsq0 = sums + H0, *sum1 = sums + 2 * H0, *sumsq1 = sums + 2 * H0 + H1;

    hipMemsetAsync(sums, 0, (size_t)(2 * H0 + 2 * H1) * sizeof(float), stream);

    reorder_W<<<(FD * FD + 255) / 256, 256, 0, stream>>>(bw, Wt);
    transpose_bf<<<dim3(H0 / 32, COMB / 32), 256, 0, stream>>>(w0, w0t, COMB, H0);
    transpose_bf<<<dim3(H1 / 32, H0 / 32), 256, 0, stream>>>(w1, w1t, H0, H1);
    gather_se<<<B_SZ, 64, 0, stream>>>(x, emb, lint, sw1, sw2, Xbf, lin);

    // S = X @ Wt^T, epilogue: Cbf = bf16(X .* S) in [4096,1536] layout
    mfma_gemm<0, FD, FD><<<dim3(FD / 128, 2 * B_SZ / 128), 256, 0, stream>>>(
        Xbf, Wt, nullptr, Xbf, Cbf, nullptr);
    // h0 = Cbf @ w0 + b0
    mfma_gemm<1, COMB, H0><<<dim3(H0 / 128, B_SZ / 128), 256, 0, stream>>>(
        Cbf, w0t, b0, nullptr, nullptr, h0);
    bn_stats<<<dim3(H0 / 256, 16), 256, 0, stream>>>(h0, H0, sum0, sumsq0);
    bn_finalize<<<H0 / 256, 256, 0, stream>>>(sum0, sumsq0, g0, be0, H0, scale0, shift0);
    bn_apply<<<(B_SZ * H0) / 256, 256, 0, stream>>>(h0, scale0, shift0, A2bf);
    // h1 = A2 @ w1 + b1
    mfma_gemm<1, H0, H1><<<dim3(H1 / 128, B_SZ / 128), 256, 0, stream>>>(
        A2bf, w1t, b1, nullptr, nullptr, h1);
    bn_stats<<<dim3(H1 / 256, 16), 256, 0, stream>>>(h1, H1, sum1, sumsq1);
    bn_finalize<<<(H1 + 255) / 256, 256, 0, stream>>>(sum1, sumsq1, g1, be1, H1, scale1, shift1);
    final_k<<<B_SZ, 64, 0, stream>>>(h1, scale1, shift1, w2, b2, lin, bias, out);
}

// Round 3
// 197.005 us; speedup vs baseline: 2.8633x; 1.2727x over previous
//
#include <hip/hip_runtime.h>

#define B_SZ 4096
#define F_SZ 24
#define V_SZ 1000
#define D_SZ 32
#define RED  8
#define FD   768      // F*D
#define COMB 1536
#define H0   1024
#define H1   512
#define EPS  1e-5f

typedef __bf16 bf16x8 __attribute__((ext_vector_type(8)));
typedef float  f32x4  __attribute__((ext_vector_type(4)));
typedef const __attribute__((address_space(1))) unsigned int* gptr_t;
typedef       __attribute__((address_space(3))) unsigned int* lptr_t;

__device__ __forceinline__ float bf2f(unsigned short u) {
    union { unsigned int i; float f; } v; v.i = ((unsigned int)u) << 16; return v.f;
}
__device__ __forceinline__ unsigned short f2bf(float f) {
    union { float f; unsigned int i; } v; v.f = f;
    unsigned int u = v.i;
    return (unsigned short)((u + 0x7FFFu + ((u >> 16) & 1u)) >> 16);
}
__device__ __forceinline__ unsigned int pack2(float a, float b) {
    return (unsigned int)f2bf(a) | ((unsigned int)f2bf(b) << 16);
}

// ---------- prep: reorder bil_W (i==j zeroed, B^T layout) + transpose w0,w1 -> bf16 [N,K] ----------
__global__ __launch_bounds__(256) void prep(const float* __restrict__ bw,
        unsigned short* __restrict__ Wt,
        const float* __restrict__ w0, unsigned short* __restrict__ w0t,
        const float* __restrict__ w1, unsigned short* __restrict__ w1t) {
    __shared__ float tile[32][33];
    int bid = blockIdx.x;
    if (bid < 2304) {                       // Wt[(i,k)][(j,l)]
        int o = bid * 256 + threadIdx.x;
        int ik = o / FD, jl = o - ik * FD;
        int i = ik >> 5, k = ik & 31, j = jl >> 5, l = jl & 31;
        Wt[o] = (i == j) ? (unsigned short)0
                         : f2bf(bw[(((size_t)i * F_SZ + j) * D_SZ + k) * D_SZ + l]);
    } else {
        const float* in; unsigned short* out; int K, N, bx, by;
        if (bid < 2304 + 1536) { int t = bid - 2304; in = w0; out = w0t; K = COMB; N = H0; bx = t & 31; by = t >> 5; }
        else                   { int t = bid - 3840; in = w1; out = w1t; K = H0;   N = H1; bx = t & 15; by = t >> 4; }
        int tx = threadIdx.x & 31, ty = threadIdx.x >> 5;
        int n0 = bx * 32, k0 = by * 32;
        #pragma unroll
        for (int r = 0; r < 32; r += 8)
            tile[ty + r][tx] = in[(size_t)(k0 + ty + r) * N + n0 + tx];
        __syncthreads();
        #pragma unroll
        for (int r = 0; r < 32; r += 8)
            out[(size_t)(n0 + ty + r) * K + k0 + tx] = f2bf(tile[tx][ty + r]);
    }
}

// ---------- gather + SENet + linear term: 4 rows/block, 1 wave/row ----------
__global__ __launch_bounds__(256) void gather_se(const int* __restrict__ x,
        const float* __restrict__ emb, const float* __restrict__ lint,
        const float* __restrict__ sw1, const float* __restrict__ sw2,
        unsigned short* __restrict__ Xbf, float* __restrict__ lin) {
    int w = threadIdx.x >> 6, lane = threadIdx.x & 63;
    int b = blockIdx.x * 4 + w;
    __shared__ int   xi[4][F_SZ];
    __shared__ float e[4][F_SZ][D_SZ];
    __shared__ float Z[4][F_SZ];
    __shared__ float r1[4][RED];
    __shared__ float Afac[4][F_SZ];
    if (lane < F_SZ) xi[w][lane] = x[b * F_SZ + lane];
    __syncthreads();
    #pragma unroll
    for (int it = 0; it < 3; it++) {
        int idx = it * 64 + lane;           // 0..191 float4s
        int f = idx >> 3, k4 = (idx & 7) * 4;
        float4 v = *(const float4*)&emb[((size_t)f * V_SZ + xi[w][f]) * D_SZ + k4];
        *(float4*)&e[w][f][k4] = v;
    }
    __syncthreads();
    if (lane < F_SZ) {
        float s = 0.f;
        #pragma unroll
        for (int k = 0; k < D_SZ; k++) s += e[w][lane][k];
        Z[w][lane] = s * (1.f / D_SZ);
    }
    __syncthreads();
    if (lane < RED) {
        float s = 0.f;
        #pragma unroll
        for (int f = 0; f < F_SZ; f++) s += Z[w][f] * sw1[lane * F_SZ + f];
        r1[w][lane] = fmaxf(s, 0.f);
    }
    __syncthreads();
    if (lane < F_SZ) {
        float s = 0.f;
        #pragma unroll
        for (int r = 0; r < RED; r++) s += r1[w][r] * sw2[lane * RED + r];
        Afac[w][lane] = 1.f / (1.f + expf(-s));
    }
    __syncthreads();
    #pragma unroll
    for (int it = 0; it < 3; it++) {
        int idx = it * 64 + lane;           // 0..191 groups of 4 cols
        int f = idx >> 3, k4 = (idx & 7) * 4;
        const float* p = &e[w][f][k4];
        uint2 u, us;
        u.x = pack2(p[0], p[1]); u.y = pack2(p[2], p[3]);
        float a = Afac[w][f];
        us.x = pack2(p[0] * a, p[1] * a); us.y = pack2(p[2] * a, p[3] * a);
        *(uint2*)&Xbf[(size_t)b * FD + idx * 4] = u;
        *(uint2*)&Xbf[(size_t)(B_SZ + b) * FD + idx * 4] = us;
    }
    float lv = (lane < F_SZ) ? lint[lane * V_SZ + xi[w][lane]] : 0.f;
    #pragma unroll
    for (int off = 32; off > 0; off >>= 1) lv += __shfl_down(lv, off);
    if (lane == 0) lin[b] = lv;
}

// ---------- MFMA GEMM: C = A[M,K](bf16) @ Bt[N,K]^T(bf16), 128xTN tile, BK=32 ----------
// MODE 0: epilogue combined = Xbf .* S -> Obf in [4096,1536] layout
// MODE 1: +bias, store bf16, fused per-column BN stats atomics
template<int MODE, int K, int N, int TN>
__global__ __launch_bounds__(256) void mfma_gemm(
        const unsigned short* __restrict__ A,
        const unsigned short* __restrict__ Bt,
        const float* __restrict__ bias,
        const unsigned short* __restrict__ Xbf,
        unsigned short* __restrict__ Obf,
        float* __restrict__ sum, float* __restrict__ sumsq) {
    constexpr int NI = TN / 32;             // 4 (TN=128) or 2 (TN=64)
    __shared__ unsigned short Abuf[128 * 32];
    __shared__ unsigned short Bbuf[TN * 32];
    const int tid  = threadIdx.x;
    const int lane = tid & 63, wv = tid >> 6;
    const int wm = (wv >> 1) * 64, wn = (wv & 1) * (TN / 2);
    const int fr = lane & 15, kq = lane >> 4;
    const int bm = blockIdx.y * 128, bn = blockIdx.x * TN;
    const int srow = tid >> 2;              // 0..63
    const int skc  = (tid & 3) * 8;         // 0,8,16,24

    f32x4 acc[4][NI];
    #pragma unroll
    for (int i = 0; i < 4; i++)
        #pragma unroll
        for (int j = 0; j < NI; j++) {
            f32x4 z = {0.f, 0.f, 0.f, 0.f};
            acc[i][j] = z;
        }

    for (int k0 = 0; k0 < K; k0 += 32) {
        #pragma unroll
        for (int c = 0; c < 2; c++) {
            const unsigned short* ga = A + (size_t)(bm + c * 64 + srow) * K + k0 + skc;
            char* la = (char*)Abuf + c * 4096 + wv * 1024;
            __builtin_amdgcn_global_load_lds((gptr_t)ga, (lptr_t)la, 16, 0, 0);
        }
        #pragma unroll
        for (int c = 0; c < TN / 64; c++) {
            const unsigned short* gb = Bt + (size_t)(bn + c * 64 + srow) * K + k0 + skc;
            char* lb = (char*)Bbuf + c * 4096 + wv * 1024;
            __builtin_amdgcn_global_load_lds((gptr_t)gb, (lptr_t)lb, 16, 0, 0);
        }
        __syncthreads();
        bf16x8 af[4], bfv[NI];
        #pragma unroll
        for (int mi = 0; mi < 4; mi++)
            af[mi] = *(const bf16x8*)&Abuf[(wm + mi * 16 + fr) * 32 + kq * 8];
        #pragma unroll
        for (int ni = 0; ni < NI; ni++)
            bfv[ni] = *(const bf16x8*)&Bbuf[(wn + ni * 16 + fr) * 32 + kq * 8];
        #pragma unroll
        for (int mi = 0; mi < 4; mi++)
            #pragma unroll
            for (int ni = 0; ni < NI; ni++)
                acc[mi][ni] = __builtin_amdgcn_mfma_f32_16x16x32_bf16(
                    af[mi], bfv[ni], acc[mi][ni], 0, 0, 0);
        __syncthreads();
    }

    if (MODE == 0) {
        #pragma unroll
        for (int mi = 0; mi < 4; mi++)
            #pragma unroll
            for (int ni = 0; ni < NI; ni++) {
                int col = bn + wn + ni * 16 + fr;
                #pragma unroll
                for (int r = 0; r < 4; r++) {
                    int row = bm + wm + mi * 16 + kq * 4 + r;
                    float xv = bf2f(Xbf[(size_t)row * FD + col]);
                    float cv = xv * acc[mi][ni][r];
                    size_t off = (row < B_SZ)
                        ? ((size_t)row * COMB + col)
                        : ((size_t)(row - B_SZ) * COMB + FD + col);
                    Obf[off] = f2bf(cv);
                }
            }
    } else {
        #pragma unroll
        for (int ni = 0; ni < NI; ni++) {
            int col = bn + wn + ni * 16 + fr;
            float bv = bias[col];
            float s = 0.f, ss = 0.f;
            #pragma unroll
            for (int mi = 0; mi < 4; mi++)
                #pragma unroll
                for (int r = 0; r < 4; r++) {
                    int row = bm + wm + mi * 16 + kq * 4 + r;
                    float v = acc[mi][ni][r] + bv;
                    Obf[(size_t)row * N + col] = f2bf(v);
                    s += v; ss += v * v;
                }
            s  += __shfl_xor(s, 16);  s  += __shfl_xor(s, 32);
            ss += __shfl_xor(ss, 16); ss += __shfl_xor(ss, 32);
            if (kq == 0) {
                atomicAdd(&sum[col], s);
                atomicAdd(&sumsq[col], ss);
            }
        }
    }
}

__global__ __launch_bounds__(256) void bn_finalize(const float* __restrict__ sum,
        const float* __restrict__ sumsq, const float* __restrict__ g,
        const float* __restrict__ be, int N,
        float* __restrict__ scale, float* __restrict__ shift) {
    int c = blockIdx.x * 256 + threadIdx.x;
    if (c >= N) return;
    float m = sum[c] * (1.f / B_SZ);
    float var = sumsq[c] * (1.f / B_SZ) - m * m;
    float rstd = rsqrtf(var + EPS);
    float sc = g[c] * rstd;
    scale[c] = sc;
    shift[c] = be[c] - m * sc;
}

// ---------- bn_apply: A2 = bf16(relu(h0bf*scale+shift)), 8 elems/thread ----------
__global__ __launch_bounds__(256) void bn_apply(const unsigned short* __restrict__ h,
        const float* __restrict__ scale, const float* __restrict__ shift,
        unsigned short* __restrict__ out) {
    int idx8 = blockIdx.x * 256 + threadIdx.x;
    int base = idx8 * 8;
    int c0 = base & (H0 - 1);
    uint4 hv = *(const uint4*)&h[base];
    unsigned int uu[4] = {hv.x, hv.y, hv.z, hv.w};
    uint4 ov;
    unsigned int oo[4];
    #pragma unroll
    for (int q = 0; q < 4; q++) {
        float v0 = bf2f((unsigned short)(uu[q] & 0xFFFF)) * scale[c0 + 2 * q] + shift[c0 + 2 * q];
        float v1 = bf2f((unsigned short)(uu[q] >> 16)) * scale[c0 + 2 * q + 1] + shift[c0 + 2 * q + 1];
        oo[q] = pack2(fmaxf(v0, 0.f), fmaxf(v1, 0.f));
    }
    ov.x = oo[0]; ov.y = oo[1]; ov.z = oo[2]; ov.w = oo[3];
    *(uint4*)&out[base] = ov;
}

// ---------- Final ----------
__global__ __launch_bounds__(64) void final_k(const unsigned short* __restrict__ h1,
        const float* __restrict__ scale1, const float* __restrict__ shift1,
        const float* __restrict__ w2, const float* __restrict__ b2,
        const float* __restrict__ lin, const float* __restrict__ bias,
        float* __restrict__ out) {
    int b = blockIdx.x;
    int t = threadIdx.x;
    int c0 = t * 8;
    uint4 hv = *(const uint4*)&h1[(size_t)b * H1 + c0];
    unsigned int uu[4] = {hv.x, hv.y, hv.z, hv.w};
    float acc = 0.f;
    #pragma unroll
    for (int q = 0; q < 4; q++) {
        int c = c0 + 2 * q;
        float v0 = bf2f((unsigned short)(uu[q] & 0xFFFF)) * scale1[c] + shift1[c];
        float v1 = bf2f((unsigned short)(uu[q] >> 16)) * scale1[c + 1] + shift1[c + 1];
        acc += fmaxf(v0, 0.f) * w2[c] + fmaxf(v1, 0.f) * w2[c + 1];
    }
    #pragma unroll
    for (int off = 32; off > 0; off >>= 1) acc += __shfl_down(acc, off);
    if (t == 0) {
        float logit = lin[b] + bias[0] + acc + b2[0];
        out[b] = 1.f / (1.f + expf(-logit));
    }
}

extern "C" void kernel_launch(void* const* d_in, const int* in_sizes, int n_in,
                              void* d_out, int out_size, void* d_ws, size_t ws_size,
                              hipStream_t stream) {
    const int*   x    = (const int*)d_in[0];
    const float* emb  = (const float*)d_in[1];
    const float* lint = (const float*)d_in[2];
    const float* bias = (const float*)d_in[3];
    const float* sw1  = (const float*)d_in[4];
    const float* sw2  = (const float*)d_in[5];
    const float* bw   = (const float*)d_in[6];
    const float* w0   = (const float*)d_in[7];
    const float* b0   = (const float*)d_in[8];
    const float* g0   = (const float*)d_in[9];
    const float* be0  = (const float*)d_in[10];
    const float* w1   = (const float*)d_in[11];
    const float* b1   = (const float*)d_in[12];
    const float* g1   = (const float*)d_in[13];
    const float* be1  = (const float*)d_in[14];
    const float* w2   = (const float*)d_in[15];
    const float* b2   = (const float*)d_in[16];
    float* out = (float*)d_out;

    char* p = (char*)d_ws;
    auto alloc = [&](size_t bytes) { char* r = p; p += (bytes + 255) & ~(size_t)255; return r; };

    unsigned short* Xbf  = (unsigned short*)alloc((size_t)2 * B_SZ * FD * 2);
    unsigned short* Wt   = (unsigned short*)alloc((size_t)FD * FD * 2);
    unsigned short* w0t  = (unsigned short*)alloc((size_t)H0 * COMB * 2);
    unsigned short* w1t  = (unsigned short*)alloc((size_t)H1 * H0 * 2);
    unsigned short* Cbf  = (unsigned short*)alloc((size_t)B_SZ * COMB * 2);
    unsigned short* h0bf = (unsigned short*)alloc((size_t)B_SZ * H0 * 2);
    unsigned short* A2bf = (unsigned short*)alloc((size_t)B_SZ * H0 * 2);
    unsigned short* h1bf = (unsigned short*)alloc((size_t)B_SZ * H1 * 2);
    float* lin = (float*)alloc(B_SZ * 4);
    float* sums   = (float*)alloc((2 * H0 + 2 * H1) * 4);
    float* scale0 = (float*)alloc(H0 * 4);
    float* shift0 = (float*)alloc(H0 * 4);
    float* scale1 = (float*)alloc(H1 * 4);
    float* shift1 = (float*)alloc(H1 * 4);
    float* sum0 = sums, *sumsq0 = sums + H0, *sum1 = sums + 2 * H0, *sumsq1 = sums + 2 * H0 + H1;

    hipMemsetAsync(sums, 0, (size_t)(2 * H0 + 2 * H1) * sizeof(float), stream);

    prep<<<4352, 256, 0, stream>>>(bw, Wt, w0, w0t, w1, w1t);
    gather_se<<<B_SZ / 4, 256, 0, stream>>>(x, emb, lint, sw1, sw2, Xbf, lin);

    // S = X @ Wt^T, epilogue: Cbf = bf16(X .* S)
    mfma_gemm<0, FD, FD, 128><<<dim3(FD / 128, 2 * B_SZ / 128), 256, 0, stream>>>(
        Xbf, Wt, nullptr, Xbf, Cbf, nullptr, nullptr);
    // h0 = Cbf @ w0 + b0 (+stats)
    mfma_gemm<1, COMB, H0, 128><<<dim3(H0 / 128, B_SZ / 128), 256, 0, stream>>>(
        Cbf, w0t, b0, nullptr, h0bf, sum0, sumsq0);
    bn_finalize<<<H0 / 256, 256, 0, stream>>>(sum0, sumsq0, g0, be0, H0, scale0, shift0);
    bn_apply<<<(B_SZ * H0) / (256 * 8), 256, 0, stream>>>(h0bf, scale0, shift0, A2bf);
    // h1 = A2 @ w1 + b1 (+stats), TN=64 -> 256 blocks
    mfma_gemm<1, H0, H1, 64><<<dim3(H1 / 64, B_SZ / 128), 256, 0, stream>>>(
        A2bf, w1t, b1, nullptr, h1bf, sum1, sumsq1);
    bn_finalize<<<(H1 + 255) / 256, 256, 0, stream>>>(sum1, sumsq1, g1, be1, H1, scale1, shift1);
    final_k<<<B_SZ, 64, 0, stream>>>(h1bf, scale1, shift1, w2, b2, lin, bias, out);
}

// Round 4
// 179.942 us; speedup vs baseline: 3.1348x; 1.0948x over previous
//
#include <hip/hip_runtime.h>

#define B_SZ 4096
#define F_SZ 24
#define V_SZ 1000
#define D_SZ 32
#define RED  8
#define FD   768      // F*D
#define COMB 1536
#define H0   1024
#define H1   512
#define EPS  1e-5f

typedef __bf16 bf16x8 __attribute__((ext_vector_type(8)));
typedef float  f32x4  __attribute__((ext_vector_type(4)));
typedef const __attribute__((address_space(1))) unsigned int* gptr_t;
typedef       __attribute__((address_space(3))) unsigned int* lptr_t;

__device__ __forceinline__ float bf2f(unsigned short u) {
    union { unsigned int i; float f; } v; v.i = ((unsigned int)u) << 16; return v.f;
}
__device__ __forceinline__ unsigned short f2bf(float f) {
    union { float f; unsigned int i; } v; v.f = f;
    unsigned int u = v.i;
    return (unsigned short)((u + 0x7FFFu + ((u >> 16) & 1u)) >> 16);
}
__device__ __forceinline__ unsigned int pack2(float a, float b) {
    return (unsigned int)f2bf(a) | ((unsigned int)f2bf(b) << 16);
}

// ---------- mega-prep: Wt reorder + w0/w1 transpose + gather/SENet + zero sums ----------
// blocks [0,1024): gather (4 rows each)
// [1024,3328): Wt   [3328,4864): w0t   [4864,5376): w1t   [5376,5388): zero sums
__global__ __launch_bounds__(256) void prep_gather(
        const int* __restrict__ x, const float* __restrict__ emb,
        const float* __restrict__ lint, const float* __restrict__ sw1,
        const float* __restrict__ sw2, const float* __restrict__ bw,
        const float* __restrict__ w0, const float* __restrict__ w1,
        unsigned short* __restrict__ Xbf, unsigned short* __restrict__ Wt,
        unsigned short* __restrict__ w0t, unsigned short* __restrict__ w1t,
        float* __restrict__ lin, float* __restrict__ sums) {
    int bid = blockIdx.x;
    int tid = threadIdx.x;
    if (bid < 1024) {
        int w = tid >> 6, lane = tid & 63;
        int b = bid * 4 + w;
        __shared__ int   xi[4][F_SZ];
        __shared__ float e[4][F_SZ][D_SZ];
        __shared__ float Z[4][F_SZ];
        __shared__ float r1[4][RED];
        __shared__ float Afac[4][F_SZ];
        if (lane < F_SZ) xi[w][lane] = x[b * F_SZ + lane];
        __syncthreads();
        #pragma unroll
        for (int it = 0; it < 3; it++) {
            int idx = it * 64 + lane;
            int f = idx >> 3, k4 = (idx & 7) * 4;
            float4 v = *(const float4*)&emb[((size_t)f * V_SZ + xi[w][f]) * D_SZ + k4];
            *(float4*)&e[w][f][k4] = v;
        }
        __syncthreads();
        if (lane < F_SZ) {
            float s = 0.f;
            #pragma unroll
            for (int k = 0; k < D_SZ; k++) s += e[w][lane][k];
            Z[w][lane] = s * (1.f / D_SZ);
        }
        __syncthreads();
        if (lane < RED) {
            float s = 0.f;
            #pragma unroll
            for (int f = 0; f < F_SZ; f++) s += Z[w][f] * sw1[lane * F_SZ + f];
            r1[w][lane] = fmaxf(s, 0.f);
        }
        __syncthreads();
        if (lane < F_SZ) {
            float s = 0.f;
            #pragma unroll
            for (int r = 0; r < RED; r++) s += r1[w][r] * sw2[lane * RED + r];
            Afac[w][lane] = 1.f / (1.f + expf(-s));
        }
        __syncthreads();
        #pragma unroll
        for (int it = 0; it < 3; it++) {
            int idx = it * 64 + lane;
            int f = idx >> 3, k4 = (idx & 7) * 4;
            const float* p = &e[w][f][k4];
            uint2 u, us;
            u.x = pack2(p[0], p[1]); u.y = pack2(p[2], p[3]);
            float a = Afac[w][f];
            us.x = pack2(p[0] * a, p[1] * a); us.y = pack2(p[2] * a, p[3] * a);
            *(uint2*)&Xbf[(size_t)b * FD + idx * 4] = u;
            *(uint2*)&Xbf[(size_t)(B_SZ + b) * FD + idx * 4] = us;
        }
        float lv = (lane < F_SZ) ? lint[lane * V_SZ + xi[w][lane]] : 0.f;
        #pragma unroll
        for (int off = 32; off > 0; off >>= 1) lv += __shfl_down(lv, off);
        if (lane == 0) lin[b] = lv;
    } else if (bid < 3328) {
        int o = (bid - 1024) * 256 + tid;
        int ik = o / FD, jl = o - ik * FD;
        int i = ik >> 5, k = ik & 31, j = jl >> 5, l = jl & 31;
        Wt[o] = (i == j) ? (unsigned short)0
                         : f2bf(bw[(((size_t)i * F_SZ + j) * D_SZ + k) * D_SZ + l]);
    } else if (bid < 5376) {
        __shared__ float tile[32][33];
        const float* in; unsigned short* out; int K, N, bx, by;
        if (bid < 4864) { int t = bid - 3328; in = w0; out = w0t; K = COMB; N = H0; bx = t & 31; by = t >> 5; }
        else            { int t = bid - 4864; in = w1; out = w1t; K = H0;   N = H1; bx = t & 15; by = t >> 4; }
        int tx = tid & 31, ty = tid >> 5;
        int n0 = bx * 32, k0 = by * 32;
        #pragma unroll
        for (int r = 0; r < 32; r += 8)
            tile[ty + r][tx] = in[(size_t)(k0 + ty + r) * N + n0 + tx];
        __syncthreads();
        #pragma unroll
        for (int r = 0; r < 32; r += 8)
            out[(size_t)(n0 + ty + r) * K + k0 + tx] = f2bf(tile[tx][ty + r]);
    } else {
        int o = (bid - 5376) * 256 + tid;   // 3072 floats
        sums[o] = 0.f;
    }
}

// ---------- MFMA GEMM: C = A[M,K](bf16) @ Bt[N,K]^T(bf16), TMxTN tile, BK=32 ----------
// MODE 0: epilogue combined = Xbf .* S -> Obf in [4096,1536] layout
// MODE 1: +bias, store bf16, fused per-column BN stats atomics
template<int MODE, int K, int N, int TM, int TN>
__global__ __launch_bounds__(256) void mfma_gemm(
        const unsigned short* __restrict__ A,
        const unsigned short* __restrict__ Bt,
        const float* __restrict__ bias,
        const unsigned short* __restrict__ Xbf,
        unsigned short* __restrict__ Obf,
        float* __restrict__ sum, float* __restrict__ sumsq) {
    constexpr int MI = TM / 32, NI = TN / 32;
    __shared__ unsigned short Abuf[TM * 32];
    __shared__ unsigned short Bbuf[TN * 32];
    const int tid  = threadIdx.x;
    const int lane = tid & 63, wv = tid >> 6;
    const int wm = (wv >> 1) * (TM / 2), wn = (wv & 1) * (TN / 2);
    const int fr = lane & 15, kq = lane >> 4;
    const int bm = blockIdx.y * TM, bn = blockIdx.x * TN;
    const int srow = tid >> 2;              // 0..63
    const int skc  = (tid & 3) * 8;         // 0,8,16,24

    f32x4 acc[MI][NI];
    #pragma unroll
    for (int i = 0; i < MI; i++)
        #pragma unroll
        for (int j = 0; j < NI; j++) {
            f32x4 z = {0.f, 0.f, 0.f, 0.f};
            acc[i][j] = z;
        }

    for (int k0 = 0; k0 < K; k0 += 32) {
        #pragma unroll
        for (int c = 0; c < TM / 64; c++) {
            const unsigned short* ga = A + (size_t)(bm + c * 64 + srow) * K + k0 + skc;
            char* la = (char*)Abuf + c * 4096 + wv * 1024;
            __builtin_amdgcn_global_load_lds((gptr_t)ga, (lptr_t)la, 16, 0, 0);
        }
        #pragma unroll
        for (int c = 0; c < TN / 64; c++) {
            const unsigned short* gb = Bt + (size_t)(bn + c * 64 + srow) * K + k0 + skc;
            char* lb = (char*)Bbuf + c * 4096 + wv * 1024;
            __builtin_amdgcn_global_load_lds((gptr_t)gb, (lptr_t)lb, 16, 0, 0);
        }
        __syncthreads();
        bf16x8 af[MI], bfv[NI];
        #pragma unroll
        for (int mi = 0; mi < MI; mi++)
            af[mi] = *(const bf16x8*)&Abuf[(wm + mi * 16 + fr) * 32 + kq * 8];
        #pragma unroll
        for (int ni = 0; ni < NI; ni++)
            bfv[ni] = *(const bf16x8*)&Bbuf[(wn + ni * 16 + fr) * 32 + kq * 8];
        #pragma unroll
        for (int mi = 0; mi < MI; mi++)
            #pragma unroll
            for (int ni = 0; ni < NI; ni++)
                acc[mi][ni] = __builtin_amdgcn_mfma_f32_16x16x32_bf16(
                    af[mi], bfv[ni], acc[mi][ni], 0, 0, 0);
        __syncthreads();
    }

    if (MODE == 0) {
        #pragma unroll
        for (int mi = 0; mi < MI; mi++)
            #pragma unroll
            for (int ni = 0; ni < NI; ni++) {
                int col = bn + wn + ni * 16 + fr;
                #pragma unroll
                for (int r = 0; r < 4; r++) {
                    int row = bm + wm + mi * 16 + kq * 4 + r;
                    float xv = bf2f(Xbf[(size_t)row * FD + col]);
                    float cv = xv * acc[mi][ni][r];
                    size_t off = (row < B_SZ)
                        ? ((size_t)row * COMB + col)
                        : ((size_t)(row - B_SZ) * COMB + FD + col);
                    Obf[off] = f2bf(cv);
                }
            }
    } else {
        #pragma unroll
        for (int ni = 0; ni < NI; ni++) {
            int col = bn + wn + ni * 16 + fr;
            float bv = bias[col];
            float s = 0.f, ss = 0.f;
            #pragma unroll
            for (int mi = 0; mi < MI; mi++)
                #pragma unroll
                for (int r = 0; r < 4; r++) {
                    int row = bm + wm + mi * 16 + kq * 4 + r;
                    float v = acc[mi][ni][r] + bv;
                    Obf[(size_t)row * N + col] = f2bf(v);
                    s += v; ss += v * v;
                }
            s  += __shfl_xor(s, 16);  s  += __shfl_xor(s, 32);
            ss += __shfl_xor(ss, 16); ss += __shfl_xor(ss, 32);
            if (kq == 0) {
                atomicAdd(&sum[col], s);
                atomicAdd(&sumsq[col], ss);
            }
        }
    }
}

// ---------- bn_apply: inline finalize + A2 = bf16(relu(h0*sc+sh)) ----------
// grid: 8 col-blocks x 64 row-blocks; block covers 128 cols x 64 rows
__global__ __launch_bounds__(256) void bn_apply(const unsigned short* __restrict__ h,
        const float* __restrict__ sum, const float* __restrict__ sumsq,
        const float* __restrict__ g, const float* __restrict__ be,
        unsigned short* __restrict__ out) {
    __shared__ float sc_s[128], sh_s[128];
    int cb = blockIdx.x & 7, rb = blockIdx.x >> 3;
    int c0 = cb * 128, r0 = rb * 64;
    int t = threadIdx.x;
    if (t < 128) {
        int c = c0 + t;
        float m = sum[c] * (1.f / B_SZ);
        float var = sumsq[c] * (1.f / B_SZ) - m * m;
        float rstd = rsqrtf(var + EPS);
        float sc = g[c] * rstd;
        sc_s[t] = sc;
        sh_s[t] = be[c] - m * sc;
    }
    __syncthreads();
    int lc = (t & 15) * 8;      // col offset within 128
    int lr = t >> 4;            // 0..15
    #pragma unroll
    for (int p = 0; p < 4; p++) {
        int row = r0 + p * 16 + lr;
        size_t base = (size_t)row * H0 + c0 + lc;
        uint4 hv = *(const uint4*)&h[base];
        unsigned int uu[4] = {hv.x, hv.y, hv.z, hv.w};
        unsigned int oo[4];
        #pragma unroll
        for (int q = 0; q < 4; q++) {
            int cc = lc + 2 * q;
            float v0 = bf2f((unsigned short)(uu[q] & 0xFFFF)) * sc_s[cc] + sh_s[cc];
            float v1 = bf2f((unsigned short)(uu[q] >> 16)) * sc_s[cc + 1] + sh_s[cc + 1];
            oo[q] = pack2(fmaxf(v0, 0.f), fmaxf(v1, 0.f));
        }
        uint4 ov; ov.x = oo[0]; ov.y = oo[1]; ov.z = oo[2]; ov.w = oo[3];
        *(uint4*)&out[base] = ov;
    }
}

// ---------- final: inline finalize1 + dot(w2) + sigmoid; 16 rows/block ----------
__global__ __launch_bounds__(256) void final_k(const unsigned short* __restrict__ h1,
        const float* __restrict__ sum, const float* __restrict__ sumsq,
        const float* __restrict__ g, const float* __restrict__ be,
        const float* __restrict__ w2, const float* __restrict__ b2,
        const float* __restrict__ lin, const float* __restrict__ bias,
        float* __restrict__ out) {
    __shared__ float sc_s[H1], sh_s[H1], w2_s[H1];
    int t = threadIdx.x;
    int wv = t >> 6, lane = t & 63;
    #pragma unroll
    for (int q = 0; q < 2; q++) {
        int c = q * 256 + t;
        float m = sum[c] * (1.f / B_SZ);
        float var = sumsq[c] * (1.f / B_SZ) - m * m;
        float rstd = rsqrtf(var + EPS);
        float sc = g[c] * rstd;
        sc_s[c] = sc;
        sh_s[c] = be[c] - m * sc;
        w2_s[c] = w2[c];
    }
    __syncthreads();
    int r0 = blockIdx.x * 16;
    #pragma unroll
    for (int i = 0; i < 4; i++) {
        int row = r0 + wv * 4 + i;
        int c0 = lane * 8;
        uint4 hv = *(const uint4*)&h1[(size_t)row * H1 + c0];
        unsigned int uu[4] = {hv.x, hv.y, hv.z, hv.w};
        float acc = 0.f;
        #pragma unroll
        for (int q = 0; q < 4; q++) {
            int c = c0 + 2 * q;
            float v0 = bf2f((unsigned short)(uu[q] & 0xFFFF)) * sc_s[c] + sh_s[c];
            float v1 = bf2f((unsigned short)(uu[q] >> 16)) * sc_s[c + 1] + sh_s[c + 1];
            acc += fmaxf(v0, 0.f) * w2_s[c] + fmaxf(v1, 0.f) * w2_s[c + 1];
        }
        #pragma unroll
        for (int off = 32; off > 0; off >>= 1) acc += __shfl_down(acc, off);
        if (lane == 0) {
            float logit = lin[row] + bias[0] + acc + b2[0];
            out[row] = 1.f / (1.f + expf(-logit));
        }
    }
}

extern "C" void kernel_launch(void* const* d_in, const int* in_sizes, int n_in,
                              void* d_out, int out_size, void* d_ws, size_t ws_size,
                              hipStream_t stream) {
    const int*   x    = (const int*)d_in[0];
    const float* emb  = (const float*)d_in[1];
    const float* lint = (const float*)d_in[2];
    const float* bias = (const float*)d_in[3];
    const float* sw1  = (const float*)d_in[4];
    const float* sw2  = (const float*)d_in[5];
    const float* bw   = (const float*)d_in[6];
    const float* w0   = (const float*)d_in[7];
    const float* b0   = (const float*)d_in[8];
    const float* g0   = (const float*)d_in[9];
    const float* be0  = (const float*)d_in[10];
    const float* w1   = (const float*)d_in[11];
    const float* b1   = (const float*)d_in[12];
    const float* g1   = (const float*)d_in[13];
    const float* be1  = (const float*)d_in[14];
    const float* w2   = (const float*)d_in[15];
    const float* b2   = (const float*)d_in[16];
    float* out = (float*)d_out;

    char* p = (char*)d_ws;
    auto alloc = [&](size_t bytes) { char* r = p; p += (bytes + 255) & ~(size_t)255; return r; };

    unsigned short* Xbf  = (unsigned short*)alloc((size_t)2 * B_SZ * FD * 2);
    unsigned short* Wt   = (unsigned short*)alloc((size_t)FD * FD * 2);
    unsigned short* w0t  = (unsigned short*)alloc((size_t)H0 * COMB * 2);
    unsigned short* w1t  = (unsigned short*)alloc((size_t)H1 * H0 * 2);
    unsigned short* Cbf  = (unsigned short*)alloc((size_t)B_SZ * COMB * 2);
    unsigned short* h0bf = (unsigned short*)alloc((size_t)B_SZ * H0 * 2);
    unsigned short* A2bf = (unsigned short*)alloc((size_t)B_SZ * H0 * 2);
    unsigned short* h1bf = (unsigned short*)alloc((size_t)B_SZ * H1 * 2);
    float* lin = (float*)alloc(B_SZ * 4);
    float* sums = (float*)alloc((2 * H0 + 2 * H1) * 4);
    float* sum0 = sums, *sumsq0 = sums + H0, *sum1 = sums + 2 * H0, *sumsq1 = sums + 2 * H0 + H1;

    prep_gather<<<5388, 256, 0, stream>>>(x, emb, lint, sw1, sw2, bw, w0, w1,
                                          Xbf, Wt, w0t, w1t, lin, sums);

    // S = X @ Wt^T, epilogue: Cbf = bf16(X .* S)   [768 blocks, 3/CU]
    mfma_gemm<0, FD, FD, 128, 64><<<dim3(FD / 64, 2 * B_SZ / 128), 256, 0, stream>>>(
        Xbf, Wt, nullptr, Xbf, Cbf, nullptr, nullptr);
    // h0 = Cbf @ w0 + b0 (+stats)   [512 blocks, 2/CU]
    mfma_gemm<1, COMB, H0, 128, 64><<<dim3(H0 / 64, B_SZ / 128), 256, 0, stream>>>(
        Cbf, w0t, b0, nullptr, h0bf, sum0, sumsq0);
    // BN0 finalize + apply fused
    bn_apply<<<512, 256, 0, stream>>>(h0bf, sum0, sumsq0, g0, be0, A2bf);
    // h1 = A2 @ w1 + b1 (+stats)   [512 blocks, 2/CU]
    mfma_gemm<1, H0, H1, 64, 64><<<dim3(H1 / 64, B_SZ / 64), 256, 0, stream>>>(
        A2bf, w1t, b1, nullptr, h1bf, sum1, sumsq1);
    // BN1 finalize + dot + sigmoid fused
    final_k<<<B_SZ / 16, 256, 0, stream>>>(h1bf, sum1, sumsq1, g1, be1,
                                           w2, b2, lin, bias, out);
}

// Round 5
// 177.336 us; speedup vs baseline: 3.1809x; 1.0147x over previous
//
#include <hip/hip_runtime.h>

#define B_SZ 4096
#define F_SZ 24
#define V_SZ 1000
#define D_SZ 32
#define RED  8
#define FD   768      // F*D
#define COMB 1536
#define H0   1024
#define H1   512
#define EPS  1e-5f

typedef __bf16 bf16x8 __attribute__((ext_vector_type(8)));
typedef float  f32x4  __attribute__((ext_vector_type(4)));
typedef const __attribute__((address_space(1))) unsigned int* gptr_t;
typedef       __attribute__((address_space(3))) unsigned int* lptr_t;

__device__ __forceinline__ float bf2f(unsigned short u) {
    union { unsigned int i; float f; } v; v.i = ((unsigned int)u) << 16; return v.f;
}
__device__ __forceinline__ unsigned short f2bf(float f) {
    union { float f; unsigned int i; } v; v.f = f;
    unsigned int u = v.i;
    return (unsigned short)((u + 0x7FFFu + ((u >> 16) & 1u)) >> 16);
}
__device__ __forceinline__ unsigned int pack2(float a, float b) {
    return (unsigned int)f2bf(a) | ((unsigned int)f2bf(b) << 16);
}

// ---------- mega-prep: Wt reorder + w0/w1 transpose + gather/SENet + zero sums ----------
__global__ __launch_bounds__(256) void prep_gather(
        const int* __restrict__ x, const float* __restrict__ emb,
        const float* __restrict__ lint, const float* __restrict__ sw1,
        const float* __restrict__ sw2, const float* __restrict__ bw,
        const float* __restrict__ w0, const float* __restrict__ w1,
        unsigned short* __restrict__ Xbf, unsigned short* __restrict__ Wt,
        unsigned short* __restrict__ w0t, unsigned short* __restrict__ w1t,
        float* __restrict__ lin, float* __restrict__ sums) {
    int bid = blockIdx.x;
    int tid = threadIdx.x;
    if (bid < 1024) {
        int w = tid >> 6, lane = tid & 63;
        int b = bid * 4 + w;
        __shared__ int   xi[4][F_SZ];
        __shared__ float e[4][F_SZ][D_SZ];
        __shared__ float Z[4][F_SZ];
        __shared__ float r1[4][RED];
        __shared__ float Afac[4][F_SZ];
        if (lane < F_SZ) xi[w][lane] = x[b * F_SZ + lane];
        __syncthreads();
        #pragma unroll
        for (int it = 0; it < 3; it++) {
            int idx = it * 64 + lane;
            int f = idx >> 3, k4 = (idx & 7) * 4;
            float4 v = *(const float4*)&emb[((size_t)f * V_SZ + xi[w][f]) * D_SZ + k4];
            *(float4*)&e[w][f][k4] = v;
        }
        __syncthreads();
        if (lane < F_SZ) {
            float s = 0.f;
            #pragma unroll
            for (int k = 0; k < D_SZ; k++) s += e[w][lane][k];
            Z[w][lane] = s * (1.f / D_SZ);
        }
        __syncthreads();
        if (lane < RED) {
            float s = 0.f;
            #pragma unroll
            for (int f = 0; f < F_SZ; f++) s += Z[w][f] * sw1[lane * F_SZ + f];
            r1[w][lane] = fmaxf(s, 0.f);
        }
        __syncthreads();
        if (lane < F_SZ) {
            float s = 0.f;
            #pragma unroll
            for (int r = 0; r < RED; r++) s += r1[w][r] * sw2[lane * RED + r];
            Afac[w][lane] = 1.f / (1.f + expf(-s));
        }
        __syncthreads();
        #pragma unroll
        for (int it = 0; it < 3; it++) {
            int idx = it * 64 + lane;
            int f = idx >> 3, k4 = (idx & 7) * 4;
            const float* p = &e[w][f][k4];
            uint2 u, us;
            u.x = pack2(p[0], p[1]); u.y = pack2(p[2], p[3]);
            float a = Afac[w][f];
            us.x = pack2(p[0] * a, p[1] * a); us.y = pack2(p[2] * a, p[3] * a);
            *(uint2*)&Xbf[(size_t)b * FD + idx * 4] = u;
            *(uint2*)&Xbf[(size_t)(B_SZ + b) * FD + idx * 4] = us;
        }
        float lv = (lane < F_SZ) ? lint[lane * V_SZ + xi[w][lane]] : 0.f;
        #pragma unroll
        for (int off = 32; off > 0; off >>= 1) lv += __shfl_down(lv, off);
        if (lane == 0) lin[b] = lv;
    } else if (bid < 3328) {
        int o = (bid - 1024) * 256 + tid;
        int ik = o / FD, jl = o - ik * FD;
        int i = ik >> 5, k = ik & 31, j = jl >> 5, l = jl & 31;
        Wt[o] = (i == j) ? (unsigned short)0
                         : f2bf(bw[(((size_t)i * F_SZ + j) * D_SZ + k) * D_SZ + l]);
    } else if (bid < 5376) {
        __shared__ float tile[32][33];
        const float* in; unsigned short* out; int K, N, bx, by;
        if (bid < 4864) { int t = bid - 3328; in = w0; out = w0t; K = COMB; N = H0; bx = t & 31; by = t >> 5; }
        else            { int t = bid - 4864; in = w1; out = w1t; K = H0;   N = H1; bx = t & 15; by = t >> 4; }
        int tx = tid & 31, ty = tid >> 5;
        int n0 = bx * 32, k0 = by * 32;
        #pragma unroll
        for (int r = 0; r < 32; r += 8)
            tile[ty + r][tx] = in[(size_t)(k0 + ty + r) * N + n0 + tx];
        __syncthreads();
        #pragma unroll
        for (int r = 0; r < 32; r += 8)
            out[(size_t)(n0 + ty + r) * K + k0 + tx] = f2bf(tile[tx][ty + r]);
    } else {
        int o = (bid - 5376) * 256 + tid;   // 3072 floats
        sums[o] = 0.f;
    }
}

// ---------- MFMA GEMM: C = A[M,K](bf16) @ Bt[N,K]^T(bf16), TMxTN tile, BK=32 ----------
// 1-D grid of GX*GY blocks, XCD-swizzled: xcd = bid&7 owns GY/8 row-bands, cols iterate fastest.
// MODE 0: epilogue combined = Xbf .* S -> Obf in [4096,1536] layout
// MODE 1: +bias, store bf16, fused per-column BN stats atomics
// MODE 2: A-operand = relu(bn(Araw)) applied during staging (BN params from psum/psumsq/g/be);
//         epilogue same as MODE 1.
template<int MODE, int K, int N, int TM, int TN, int GX, int GY>
__global__ __launch_bounds__(256) void mfma_gemm(
        const unsigned short* __restrict__ A,
        const unsigned short* __restrict__ Bt,
        const float* __restrict__ bias,
        const unsigned short* __restrict__ Xbf,
        unsigned short* __restrict__ Obf,
        float* __restrict__ sum, float* __restrict__ sumsq,
        const float* __restrict__ psum, const float* __restrict__ psumsq,
        const float* __restrict__ g, const float* __restrict__ be) {
    constexpr int MI = TM / 32, NI = TN / 32;
    __shared__ unsigned short Abuf[TM * 32];
    __shared__ unsigned short Bbuf[TN * 32];
    __shared__ float sc_s[MODE == 2 ? K : 1];
    __shared__ float sh_s[MODE == 2 ? K : 1];
    const int tid  = threadIdx.x;
    const int lane = tid & 63, wv = tid >> 6;
    const int wm = (wv >> 1) * (TM / 2), wn = (wv & 1) * (TN / 2);
    const int fr = lane & 15, kq = lane >> 4;
    // XCD swizzle
    const int bid = blockIdx.x;
    const int xcd = bid & 7, slot = bid >> 3;
    const int rowb = xcd * (GY / 8) + slot / GX;
    const int colb = slot % GX;
    const int bm = rowb * TM, bn = colb * TN;
    const int srow = tid >> 2;              // 0..63
    const int skc  = (tid & 3) * 8;         // 0,8,16,24

    if (MODE == 2) {
        #pragma unroll
        for (int q = 0; q < K / 256; q++) {
            int c = q * 256 + tid;
            float m = psum[c] * (1.f / B_SZ);
            float var = psumsq[c] * (1.f / B_SZ) - m * m;
            float rstd = rsqrtf(var + EPS);
            float sc = g[c] * rstd;
            sc_s[c] = sc;
            sh_s[c] = be[c] - m * sc;
        }
        __syncthreads();
    }

    f32x4 acc[MI][NI];
    #pragma unroll
    for (int i = 0; i < MI; i++)
        #pragma unroll
        for (int j = 0; j < NI; j++) {
            f32x4 z = {0.f, 0.f, 0.f, 0.f};
            acc[i][j] = z;
        }

    for (int k0 = 0; k0 < K; k0 += 32) {
        if (MODE == 2) {
            // stage A through VGPRs with bn+relu applied (TM must be 64)
            uint4 hv = *(const uint4*)&A[(size_t)(bm + srow) * K + k0 + skc];
            unsigned int uu[4] = {hv.x, hv.y, hv.z, hv.w};
            unsigned int oo[4];
            #pragma unroll
            for (int q = 0; q < 4; q++) {
                int c = k0 + skc + 2 * q;
                float v0 = bf2f((unsigned short)(uu[q] & 0xFFFF)) * sc_s[c] + sh_s[c];
                float v1 = bf2f((unsigned short)(uu[q] >> 16)) * sc_s[c + 1] + sh_s[c + 1];
                oo[q] = pack2(fmaxf(v0, 0.f), fmaxf(v1, 0.f));
            }
            uint4 ov; ov.x = oo[0]; ov.y = oo[1]; ov.z = oo[2]; ov.w = oo[3];
            *(uint4*)&Abuf[srow * 32 + skc] = ov;
        } else {
            #pragma unroll
            for (int c = 0; c < TM / 64; c++) {
                const unsigned short* ga = A + (size_t)(bm + c * 64 + srow) * K + k0 + skc;
                char* la = (char*)Abuf + c * 4096 + wv * 1024;
                __builtin_amdgcn_global_load_lds((gptr_t)ga, (lptr_t)la, 16, 0, 0);
            }
        }
        #pragma unroll
        for (int c = 0; c < TN / 64; c++) {
            const unsigned short* gb = Bt + (size_t)(bn + c * 64 + srow) * K + k0 + skc;
            char* lb = (char*)Bbuf + c * 4096 + wv * 1024;
            __builtin_amdgcn_global_load_lds((gptr_t)gb, (lptr_t)lb, 16, 0, 0);
        }
        __syncthreads();
        bf16x8 af[MI], bfv[NI];
        #pragma unroll
        for (int mi = 0; mi < MI; mi++)
            af[mi] = *(const bf16x8*)&Abuf[(wm + mi * 16 + fr) * 32 + kq * 8];
        #pragma unroll
        for (int ni = 0; ni < NI; ni++)
            bfv[ni] = *(const bf16x8*)&Bbuf[(wn + ni * 16 + fr) * 32 + kq * 8];
        #pragma unroll
        for (int mi = 0; mi < MI; mi++)
            #pragma unroll
            for (int ni = 0; ni < NI; ni++)
                acc[mi][ni] = __builtin_amdgcn_mfma_f32_16x16x32_bf16(
                    af[mi], bfv[ni], acc[mi][ni], 0, 0, 0);
        __syncthreads();
    }

    if (MODE == 0) {
        #pragma unroll
        for (int mi = 0; mi < MI; mi++)
            #pragma unroll
            for (int ni = 0; ni < NI; ni++) {
                int col = bn + wn + ni * 16 + fr;
                #pragma unroll
                for (int r = 0; r < 4; r++) {
                    int row = bm + wm + mi * 16 + kq * 4 + r;
                    float xv = bf2f(Xbf[(size_t)row * FD + col]);
                    float cv = xv * acc[mi][ni][r];
                    size_t off = (row < B_SZ)
                        ? ((size_t)row * COMB + col)
                        : ((size_t)(row - B_SZ) * COMB + FD + col);
                    Obf[off] = f2bf(cv);
                }
            }
    } else {
        #pragma unroll
        for (int ni = 0; ni < NI; ni++) {
            int col = bn + wn + ni * 16 + fr;
            float bv = bias[col];
            float s = 0.f, ss = 0.f;
            #pragma unroll
            for (int mi = 0; mi < MI; mi++)
                #pragma unroll
                for (int r = 0; r < 4; r++) {
                    int row = bm + wm + mi * 16 + kq * 4 + r;
                    float v = acc[mi][ni][r] + bv;
                    Obf[(size_t)row * N + col] = f2bf(v);
                    s += v; ss += v * v;
                }
            s  += __shfl_xor(s, 16);  s  += __shfl_xor(s, 32);
            ss += __shfl_xor(ss, 16); ss += __shfl_xor(ss, 32);
            if (kq == 0) {
                atomicAdd(&sum[col], s);
                atomicAdd(&sumsq[col], ss);
            }
        }
    }
}

// ---------- final: inline finalize1 + dot(w2) + sigmoid; 16 rows/block ----------
__global__ __launch_bounds__(256) void final_k(const unsigned short* __restrict__ h1,
        const float* __restrict__ sum, const float* __restrict__ sumsq,
        const float* __restrict__ g, const float* __restrict__ be,
        const float* __restrict__ w2, const float* __restrict__ b2,
        const float* __restrict__ lin, const float* __restrict__ bias,
        float* __restrict__ out) {
    __shared__ float sc_s[H1], sh_s[H1], w2_s[H1];
    int t = threadIdx.x;
    int wv = t >> 6, lane = t & 63;
    #pragma unroll
    for (int q = 0; q < 2; q++) {
        int c = q * 256 + t;
        float m = sum[c] * (1.f / B_SZ);
        float var = sumsq[c] * (1.f / B_SZ) - m * m;
        float rstd = rsqrtf(var + EPS);
        float sc = g[c] * rstd;
        sc_s[c] = sc;
        sh_s[c] = be[c] - m * sc;
        w2_s[c] = w2[c];
    }
    __syncthreads();
    int r0 = blockIdx.x * 16;
    #pragma unroll
    for (int i = 0; i < 4; i++) {
        int row = r0 + wv * 4 + i;
        int c0 = lane * 8;
        uint4 hv = *(const uint4*)&h1[(size_t)row * H1 + c0];
        unsigned int uu[4] = {hv.x, hv.y, hv.z, hv.w};
        float acc = 0.f;
        #pragma unroll
        for (int q = 0; q < 4; q++) {
            int c = c0 + 2 * q;
            float v0 = bf2f((unsigned short)(uu[q] & 0xFFFF)) * sc_s[c] + sh_s[c];
            float v1 = bf2f((unsigned short)(uu[q] >> 16)) * sc_s[c + 1] + sh_s[c + 1];
            acc += fmaxf(v0, 0.f) * w2_s[c] + fmaxf(v1, 0.f) * w2_s[c + 1];
        }
        #pragma unroll
        for (int off = 32; off > 0; off >>= 1) acc += __shfl_down(acc, off);
        if (lane == 0) {
            float logit = lin[row] + bias[0] + acc + b2[0];
            out[row] = 1.f / (1.f + expf(-logit));
        }
    }
}

extern "C" void kernel_launch(void* const* d_in, const int* in_sizes, int n_in,
                              void* d_out, int out_size, void* d_ws, size_t ws_size,
                              hipStream_t stream) {
    const int*   x    = (const int*)d_in[0];
    const float* emb  = (const float*)d_in[1];
    const float* lint = (const float*)d_in[2];
    const float* bias = (const float*)d_in[3];
    const float* sw1  = (const float*)d_in[4];
    const float* sw2  = (const float*)d_in[5];
    const float* bw   = (const float*)d_in[6];
    const float* w0   = (const float*)d_in[7];
    const float* b0   = (const float*)d_in[8];
    const float* g0   = (const float*)d_in[9];
    const float* be0  = (const float*)d_in[10];
    const float* w1   = (const float*)d_in[11];
    const float* b1   = (const float*)d_in[12];
    const float* g1   = (const float*)d_in[13];
    const float* be1  = (const float*)d_in[14];
    const float* w2   = (const float*)d_in[15];
    const float* b2   = (const float*)d_in[16];
    float* out = (float*)d_out;

    char* p = (char*)d_ws;
    auto alloc = [&](size_t bytes) { char* r = p; p += (bytes + 255) & ~(size_t)255; return r; };

    unsigned short* Xbf  = (unsigned short*)alloc((size_t)2 * B_SZ * FD * 2);
    unsigned short* Wt   = (unsigned short*)alloc((size_t)FD * FD * 2);
    unsigned short* w0t  = (unsigned short*)alloc((size_t)H0 * COMB * 2);
    unsigned short* w1t  = (unsigned short*)alloc((size_t)H1 * H0 * 2);
    unsigned short* Cbf  = (unsigned short*)alloc((size_t)B_SZ * COMB * 2);
    unsigned short* h0bf = (unsigned short*)alloc((size_t)B_SZ * H0 * 2);
    unsigned short* h1bf = (unsigned short*)alloc((size_t)B_SZ * H1 * 2);
    float* lin = (float*)alloc(B_SZ * 4);
    float* sums = (float*)alloc((2 * H0 + 2 * H1) * 4);
    float* sum0 = sums, *sumsq0 = sums + H0, *sum1 = sums + 2 * H0, *sumsq1 = sums + 2 * H0 + H1;

    prep_gather<<<5388, 256, 0, stream>>>(x, emb, lint, sw1, sw2, bw, w0, w1,
                                          Xbf, Wt, w0t, w1t, lin, sums);

    // S = X @ Wt^T, epilogue: Cbf = bf16(X .* S)   [768 blocks, XCD-swizzled]
    mfma_gemm<0, FD, FD, 128, 64, 12, 64><<<768, 256, 0, stream>>>(
        Xbf, Wt, nullptr, Xbf, Cbf, nullptr, nullptr, nullptr, nullptr, nullptr, nullptr);
    // h0 = Cbf @ w0 + b0 (+stats)   [512 blocks]
    mfma_gemm<1, COMB, H0, 128, 64, 16, 32><<<512, 256, 0, stream>>>(
        Cbf, w0t, b0, nullptr, h0bf, sum0, sumsq0, nullptr, nullptr, nullptr, nullptr);
    // h1 = relu(bn(h0)) @ w1 + b1 (+stats), BN0 finalize+apply fused into A-staging
    mfma_gemm<2, H0, H1, 64, 64, 8, 64><<<512, 256, 0, stream>>>(
        h0bf, w1t, b1, nullptr, h1bf, sum1, sumsq1, sum0, sumsq0, g0, be0);
    // BN1 finalize + dot + sigmoid fused
    final_k<<<B_SZ / 16, 256, 0, stream>>>(h1bf, sum1, sumsq1, g1, be1,
                                           w2, b2, lin, bias, out);
}

// Round 6
// 165.827 us; speedup vs baseline: 3.4016x; 1.0694x over previous
//
#include <hip/hip_runtime.h>

#define B_SZ 4096
#define F_SZ 24
#define V_SZ 1000
#define D_SZ 32
#define RED  8
#define FD   768      // F*D
#define COMB 1536
#define H0   1024
#define H1   512
#define EPS  1e-5f

typedef __bf16 bf16x8 __attribute__((ext_vector_type(8)));
typedef float  f32x4  __attribute__((ext_vector_type(4)));
typedef const __attribute__((address_space(1))) unsigned int* gptr_t;
typedef       __attribute__((address_space(3))) unsigned int* lptr_t;

__device__ __forceinline__ float bf2f(unsigned short u) {
    union { unsigned int i; float f; } v; v.i = ((unsigned int)u) << 16; return v.f;
}
__device__ __forceinline__ unsigned short f2bf(float f) {
    union { float f; unsigned int i; } v; v.f = f;
    unsigned int u = v.i;
    return (unsigned short)((u + 0x7FFFu + ((u >> 16) & 1u)) >> 16);
}
__device__ __forceinline__ unsigned int pack2(float a, float b) {
    return (unsigned int)f2bf(a) | ((unsigned int)f2bf(b) << 16);
}

// ---------- mega-prep: Wt reorder + w0/w1 transpose + gather/SENet + zero sums ----------
__global__ __launch_bounds__(256) void prep_gather(
        const int* __restrict__ x, const float* __restrict__ emb,
        const float* __restrict__ lint, const float* __restrict__ sw1,
        const float* __restrict__ sw2, const float* __restrict__ bw,
        const float* __restrict__ w0, const float* __restrict__ w1,
        unsigned short* __restrict__ Xbf, unsigned short* __restrict__ Wt,
        unsigned short* __restrict__ w0t, unsigned short* __restrict__ w1t,
        float* __restrict__ lin, float* __restrict__ sums) {
    int bid = blockIdx.x;
    int tid = threadIdx.x;
    if (bid < 1024) {
        int w = tid >> 6, lane = tid & 63;
        int b = bid * 4 + w;
        __shared__ int   xi[4][F_SZ];
        __shared__ float e[4][F_SZ][D_SZ];
        __shared__ float Z[4][F_SZ];
        __shared__ float r1[4][RED];
        __shared__ float Afac[4][F_SZ];
        if (lane < F_SZ) xi[w][lane] = x[b * F_SZ + lane];
        __syncthreads();
        #pragma unroll
        for (int it = 0; it < 3; it++) {
            int idx = it * 64 + lane;
            int f = idx >> 3, k4 = (idx & 7) * 4;
            float4 v = *(const float4*)&emb[((size_t)f * V_SZ + xi[w][f]) * D_SZ + k4];
            *(float4*)&e[w][f][k4] = v;
        }
        __syncthreads();
        if (lane < F_SZ) {
            float s = 0.f;
            #pragma unroll
            for (int k = 0; k < D_SZ; k++) s += e[w][lane][k];
            Z[w][lane] = s * (1.f / D_SZ);
        }
        __syncthreads();
        if (lane < RED) {
            float s = 0.f;
            #pragma unroll
            for (int f = 0; f < F_SZ; f++) s += Z[w][f] * sw1[lane * F_SZ + f];
            r1[w][lane] = fmaxf(s, 0.f);
        }
        __syncthreads();
        if (lane < F_SZ) {
            float s = 0.f;
            #pragma unroll
            for (int r = 0; r < RED; r++) s += r1[w][r] * sw2[lane * RED + r];
            Afac[w][lane] = 1.f / (1.f + expf(-s));
        }
        __syncthreads();
        #pragma unroll
        for (int it = 0; it < 3; it++) {
            int idx = it * 64 + lane;
            int f = idx >> 3, k4 = (idx & 7) * 4;
            const float* p = &e[w][f][k4];
            uint2 u, us;
            u.x = pack2(p[0], p[1]); u.y = pack2(p[2], p[3]);
            float a = Afac[w][f];
            us.x = pack2(p[0] * a, p[1] * a); us.y = pack2(p[2] * a, p[3] * a);
            *(uint2*)&Xbf[(size_t)b * FD + idx * 4] = u;
            *(uint2*)&Xbf[(size_t)(B_SZ + b) * FD + idx * 4] = us;
        }
        float lv = (lane < F_SZ) ? lint[lane * V_SZ + xi[w][lane]] : 0.f;
        #pragma unroll
        for (int off = 32; off > 0; off >>= 1) lv += __shfl_down(lv, off);
        if (lane == 0) lin[b] = lv;
    } else if (bid < 3328) {
        int o = (bid - 1024) * 256 + tid;
        int ik = o / FD, jl = o - ik * FD;
        int i = ik >> 5, k = ik & 31, j = jl >> 5, l = jl & 31;
        Wt[o] = (i == j) ? (unsigned short)0
                         : f2bf(bw[(((size_t)i * F_SZ + j) * D_SZ + k) * D_SZ + l]);
    } else if (bid < 5376) {
        __shared__ float tile[32][33];
        const float* in; unsigned short* out; int K, N, bx, by;
        if (bid < 4864) { int t = bid - 3328; in = w0; out = w0t; K = COMB; N = H0; bx = t & 31; by = t >> 5; }
        else            { int t = bid - 4864; in = w1; out = w1t; K = H0;   N = H1; bx = t & 15; by = t >> 4; }
        int tx = tid & 31, ty = tid >> 5;
        int n0 = bx * 32, k0 = by * 32;
        #pragma unroll
        for (int r = 0; r < 32; r += 8)
            tile[ty + r][tx] = in[(size_t)(k0 + ty + r) * N + n0 + tx];
        __syncthreads();
        #pragma unroll
        for (int r = 0; r < 32; r += 8)
            out[(size_t)(n0 + ty + r) * K + k0 + tx] = f2bf(tile[tx][ty + r]);
    } else {
        int o = (bid - 5376) * 256 + tid;   // 3072 floats
        sums[o] = 0.f;
    }
}

// ---------- MFMA GEMM: C = A[M,K](bf16) @ Bt[N,K]^T(bf16), TMxTN tile, BK=64 (2 subtiles) ----------
// 1-D grid, XCD-swizzled. MODE 0: C = Xbf .* S -> Obf[4096,1536]. MODE 1: +bias, bf16 store,
// fused BN stats. MODE 2: A = relu(bn(Araw)) staged via prefetched VGPRs; epilogue as MODE 1.
template<int MODE, int K, int N, int TM, int TN, int GX, int GY>
__global__ __launch_bounds__(256) void mfma_gemm(
        const unsigned short* __restrict__ A,
        const unsigned short* __restrict__ Bt,
        const float* __restrict__ bias,
        const unsigned short* __restrict__ Xbf,
        unsigned short* __restrict__ Obf,
        float* __restrict__ sum, float* __restrict__ sumsq,
        const float* __restrict__ psum, const float* __restrict__ psumsq,
        const float* __restrict__ g, const float* __restrict__ be) {
    constexpr int MI = TM / 32, NI = TN / 32;
    constexpr int CLD = TN + 4;                       // padded fp32 C stride
    constexpr int STAGE = (TM + TN) * 128;            // bytes: 64 kcols x 2B, 2 subtiles
    constexpr int CST   = TM * CLD * 4;
    constexpr int SMEM  = STAGE > CST ? STAGE : CST;
    __shared__ __align__(16) char smem[SMEM];
    unsigned short* Abuf = (unsigned short*)smem;                   // [2][TM*32]
    unsigned short* Bbuf = (unsigned short*)(smem + TM * 128);      // [2][TN*32]
    float* Cst = (float*)smem;
    __shared__ float sc_s[MODE == 2 ? K : 1];
    __shared__ float sh_s[MODE == 2 ? K : 1];
    const int tid  = threadIdx.x;
    const int lane = tid & 63, wv = tid >> 6;
    const int wm = (wv >> 1) * (TM / 2), wn = (wv & 1) * (TN / 2);
    const int fr = lane & 15, kq = lane >> 4;
    const int bid = blockIdx.x;
    const int xcd = bid & 7, slot = bid >> 3;
    const int rowb = xcd * (GY / 8) + slot / GX;
    const int colb = slot % GX;
    const int bm = rowb * TM, bn = colb * TN;
    const int srow = tid >> 2;              // 0..63
    const int skc  = (tid & 3) * 8;         // 0,8,16,24 (shorts)

    if (MODE == 2) {
        #pragma unroll
        for (int q = 0; q < K / 256; q++) {
            int c = q * 256 + tid;
            float m = psum[c] * (1.f / B_SZ);
            float var = psumsq[c] * (1.f / B_SZ) - m * m;
            float rstd = rsqrtf(var + EPS);
            float sc = g[c] * rstd;
            sc_s[c] = sc;
            sh_s[c] = be[c] - m * sc;
        }
        __syncthreads();
    }

    f32x4 acc[MI][NI];
    #pragma unroll
    for (int i = 0; i < MI; i++)
        #pragma unroll
        for (int j = 0; j < NI; j++) {
            f32x4 z = {0.f, 0.f, 0.f, 0.f};
            acc[i][j] = z;
        }

    uint4 hvA[2];
    if (MODE == 2) {
        #pragma unroll
        for (int s = 0; s < 2; s++)
            hvA[s] = *(const uint4*)&A[(size_t)(bm + srow) * K + 32 * s + skc];
    }

    for (int k0 = 0; k0 < K; k0 += 64) {
        if (MODE == 2) {
            #pragma unroll
            for (int s = 0; s < 2; s++) {
                unsigned int uu[4] = {hvA[s].x, hvA[s].y, hvA[s].z, hvA[s].w};
                unsigned int oo[4];
                #pragma unroll
                for (int q = 0; q < 4; q++) {
                    int c = k0 + 32 * s + skc + 2 * q;
                    float v0 = bf2f((unsigned short)(uu[q] & 0xFFFF)) * sc_s[c] + sh_s[c];
                    float v1 = bf2f((unsigned short)(uu[q] >> 16)) * sc_s[c + 1] + sh_s[c + 1];
                    oo[q] = pack2(fmaxf(v0, 0.f), fmaxf(v1, 0.f));
                }
                uint4 ov; ov.x = oo[0]; ov.y = oo[1]; ov.z = oo[2]; ov.w = oo[3];
                *(uint4*)&Abuf[s * TM * 32 + srow * 32 + skc] = ov;
            }
            if (k0 + 64 < K) {      // prefetch next iteration (overlaps MFMA below)
                #pragma unroll
                for (int s = 0; s < 2; s++)
                    hvA[s] = *(const uint4*)&A[(size_t)(bm + srow) * K + k0 + 64 + 32 * s + skc];
            }
        } else {
            #pragma unroll
            for (int s = 0; s < 2; s++)
                #pragma unroll
                for (int c = 0; c < TM / 64; c++) {
                    const unsigned short* ga = A + (size_t)(bm + c * 64 + srow) * K + k0 + 32 * s + skc;
                    char* la = smem + s * TM * 64 + c * 4096 + wv * 1024;
                    __builtin_amdgcn_global_load_lds((gptr_t)ga, (lptr_t)la, 16, 0, 0);
                }
        }
        #pragma unroll
        for (int s = 0; s < 2; s++)
            #pragma unroll
            for (int c = 0; c < TN / 64; c++) {
                const unsigned short* gb = Bt + (size_t)(bn + c * 64 + srow) * K + k0 + 32 * s + skc;
                char* lb = smem + TM * 128 + s * TN * 64 + c * 4096 + wv * 1024;
                __builtin_amdgcn_global_load_lds((gptr_t)gb, (lptr_t)lb, 16, 0, 0);
            }
        __syncthreads();
        #pragma unroll
        for (int s = 0; s < 2; s++) {
            bf16x8 af[MI], bfv[NI];
            #pragma unroll
            for (int mi = 0; mi < MI; mi++)
                af[mi] = *(const bf16x8*)&Abuf[s * TM * 32 + (wm + mi * 16 + fr) * 32 + kq * 8];
            #pragma unroll
            for (int ni = 0; ni < NI; ni++)
                bfv[ni] = *(const bf16x8*)&Bbuf[s * TN * 32 + (wn + ni * 16 + fr) * 32 + kq * 8];
            #pragma unroll
            for (int mi = 0; mi < MI; mi++)
                #pragma unroll
                for (int ni = 0; ni < NI; ni++)
                    acc[mi][ni] = __builtin_amdgcn_mfma_f32_16x16x32_bf16(
                        af[mi], bfv[ni], acc[mi][ni], 0, 0, 0);
        }
        __syncthreads();
    }

    // ---- stats (MODE 1/2) in register layout, with bias folded in ----
    if (MODE != 0) {
        #pragma unroll
        for (int ni = 0; ni < NI; ni++) {
            int col = bn + wn + ni * 16 + fr;
            float bv = bias[col];
            float s = 0.f, ss = 0.f;
            #pragma unroll
            for (int mi = 0; mi < MI; mi++)
                #pragma unroll
                for (int r = 0; r < 4; r++) {
                    float v = acc[mi][ni][r] + bv;
                    acc[mi][ni][r] = v;
                    s += v; ss += v * v;
                }
            s  += __shfl_xor(s, 16);  s  += __shfl_xor(s, 32);
            ss += __shfl_xor(ss, 16); ss += __shfl_xor(ss, 32);
            if (kq == 0) {
                atomicAdd(&sum[col], s);
                atomicAdd(&sumsq[col], ss);
            }
        }
    }

    // ---- stage fp32 C tile to LDS, then coalesced vectorized epilogue ----
    #pragma unroll
    for (int mi = 0; mi < MI; mi++)
        #pragma unroll
        for (int ni = 0; ni < NI; ni++) {
            int lrow = wm + mi * 16 + kq * 4;
            int lcol = wn + ni * 16 + fr;
            #pragma unroll
            for (int r = 0; r < 4; r++)
                Cst[(lrow + r) * CLD + lcol] = acc[mi][ni][r];
        }
    __syncthreads();
    #pragma unroll
    for (int ps = 0; ps < TM / 32; ps++) {
        int rl = ps * 32 + (tid >> 3);
        int cl = (tid & 7) * 8;
        float4 va = *(const float4*)&Cst[rl * CLD + cl];
        float4 vb = *(const float4*)&Cst[rl * CLD + cl + 4];
        float v[8] = {va.x, va.y, va.z, va.w, vb.x, vb.y, vb.z, vb.w};
        int grow = bm + rl, gcol = bn + cl;
        if (MODE == 0) {
            uint4 xv = *(const uint4*)&Xbf[(size_t)grow * FD + gcol];
            unsigned int xu[4] = {xv.x, xv.y, xv.z, xv.w};
            unsigned int oo[4];
            #pragma unroll
            for (int q = 0; q < 4; q++) {
                float x0 = bf2f((unsigned short)(xu[q] & 0xFFFF));
                float x1 = bf2f((unsigned short)(xu[q] >> 16));
                oo[q] = pack2(x0 * v[2 * q], x1 * v[2 * q + 1]);
            }
            uint4 ov; ov.x = oo[0]; ov.y = oo[1]; ov.z = oo[2]; ov.w = oo[3];
            size_t off = (grow < B_SZ)
                ? ((size_t)grow * COMB + gcol)
                : ((size_t)(grow - B_SZ) * COMB + FD + gcol);
            *(uint4*)&Obf[off] = ov;
        } else {
            unsigned int oo[4];
            #pragma unroll
            for (int q = 0; q < 4; q++)
                oo[q] = pack2(v[2 * q], v[2 * q + 1]);
            uint4 ov; ov.x = oo[0]; ov.y = oo[1]; ov.z = oo[2]; ov.w = oo[3];
            *(uint4*)&Obf[(size_t)grow * N + gcol] = ov;
        }
    }
}

// ---------- final: inline finalize1 + dot(w2) + sigmoid; 16 rows/block ----------
__global__ __launch_bounds__(256) void final_k(const unsigned short* __restrict__ h1,
        const float* __restrict__ sum, const float* __restrict__ sumsq,
        const float* __restrict__ g, const float* __restrict__ be,
        const float* __restrict__ w2, const float* __restrict__ b2,
        const float* __restrict__ lin, const float* __restrict__ bias,
        float* __restrict__ out) {
    __shared__ float sc_s[H1], sh_s[H1], w2_s[H1];
    int t = threadIdx.x;
    int wv = t >> 6, lane = t & 63;
    #pragma unroll
    for (int q = 0; q < 2; q++) {
        int c = q * 256 + t;
        float m = sum[c] * (1.f / B_SZ);
        float var = sumsq[c] * (1.f / B_SZ) - m * m;
        float rstd = rsqrtf(var + EPS);
        float sc = g[c] * rstd;
        sc_s[c] = sc;
        sh_s[c] = be[c] - m * sc;
        w2_s[c] = w2[c];
    }
    __syncthreads();
    int r0 = blockIdx.x * 16;
    #pragma unroll
    for (int i = 0; i < 4; i++) {
        int row = r0 + wv * 4 + i;
        int c0 = lane * 8;
        uint4 hv = *(const uint4*)&h1[(size_t)row * H1 + c0];
        unsigned int uu[4] = {hv.x, hv.y, hv.z, hv.w};
        float acc = 0.f;
        #pragma unroll
        for (int q = 0; q < 4; q++) {
            int c = c0 + 2 * q;
            float v0 = bf2f((unsigned short)(uu[q] & 0xFFFF)) * sc_s[c] + sh_s[c];
            float v1 = bf2f((unsigned short)(uu[q] >> 16)) * sc_s[c + 1] + sh_s[c + 1];
            acc += fmaxf(v0, 0.f) * w2_s[c] + fmaxf(v1, 0.f) * w2_s[c + 1];
        }
        #pragma unroll
        for (int off = 32; off > 0; off >>= 1) acc += __shfl_down(acc, off);
        if (lane == 0) {
            float logit = lin[row] + bias[0] + acc + b2[0];
            out[row] = 1.f / (1.f + expf(-logit));
        }
    }
}

extern "C" void kernel_launch(void* const* d_in, const int* in_sizes, int n_in,
                              void* d_out, int out_size, void* d_ws, size_t ws_size,
                              hipStream_t stream) {
    const int*   x    = (const int*)d_in[0];
    const float* emb  = (const float*)d_in[1];
    const float* lint = (const float*)d_in[2];
    const float* bias = (const float*)d_in[3];
    const float* sw1  = (const float*)d_in[4];
    const float* sw2  = (const float*)d_in[5];
    const float* bw   = (const float*)d_in[6];
    const float* w0   = (const float*)d_in[7];
    const float* b0   = (const float*)d_in[8];
    const float* g0   = (const float*)d_in[9];
    const float* be0  = (const float*)d_in[10];
    const float* w1   = (const float*)d_in[11];
    const float* b1   = (const float*)d_in[12];
    const float* g1   = (const float*)d_in[13];
    const float* be1  = (const float*)d_in[14];
    const float* w2   = (const float*)d_in[15];
    const float* b2   = (const float*)d_in[16];
    float* out = (float*)d_out;

    char* p = (char*)d_ws;
    auto alloc = [&](size_t bytes) { char* r = p; p += (bytes + 255) & ~(size_t)255; return r; };

    unsigned short* Xbf  = (unsigned short*)alloc((size_t)2 * B_SZ * FD * 2);
    unsigned short* Wt   = (unsigned short*)alloc((size_t)FD * FD * 2);
    unsigned short* w0t  = (unsigned short*)alloc((size_t)H0 * COMB * 2);
    unsigned short* w1t  = (unsigned short*)alloc((size_t)H1 * H0 * 2);
    unsigned short* Cbf  = (unsigned short*)alloc((size_t)B_SZ * COMB * 2);
    unsigned short* h0bf = (unsigned short*)alloc((size_t)B_SZ * H0 * 2);
    unsigned short* h1bf = (unsigned short*)alloc((size_t)B_SZ * H1 * 2);
    float* lin = (float*)alloc(B_SZ * 4);
    float* sums = (float*)alloc((2 * H0 + 2 * H1) * 4);
    float* sum0 = sums, *sumsq0 = sums + H0, *sum1 = sums + 2 * H0, *sumsq1 = sums + 2 * H0 + H1;

    prep_gather<<<5388, 256, 0, stream>>>(x, emb, lint, sw1, sw2, bw, w0, w1,
                                          Xbf, Wt, w0t, w1t, lin, sums);

    // S = X @ Wt^T, epilogue: Cbf = bf16(X .* S)   [768 blocks, XCD-swizzled]
    mfma_gemm<0, FD, FD, 128, 64, 12, 64><<<768, 256, 0, stream>>>(
        Xbf, Wt, nullptr, Xbf, Cbf, nullptr, nullptr, nullptr, nullptr, nullptr, nullptr);
    // h0 = Cbf @ w0 + b0 (+stats)   [512 blocks]
    mfma_gemm<1, COMB, H0, 128, 64, 16, 32><<<512, 256, 0, stream>>>(
        Cbf, w0t, b0, nullptr, h0bf, sum0, sumsq0, nullptr, nullptr, nullptr, nullptr);
    // h1 = relu(bn(h0)) @ w1 + b1 (+stats), BN0 finalize+apply fused into A-staging
    mfma_gemm<2, H0, H1, 64, 64, 8, 64><<<512, 256, 0, stream>>>(
        h0bf, w1t, b1, nullptr, h1bf, sum1, sumsq1, sum0, sumsq0, g0, be0);
    // BN1 finalize + dot + sigmoid fused
    final_k<<<B_SZ / 16, 256, 0, stream>>>(h1bf, sum1, sumsq1, g1, be1,
                                           w2, b2, lin, bias, out);
}

// Round 7
// 160.679 us; speedup vs baseline: 3.5106x; 1.0320x over previous
//
#include <hip/hip_runtime.h>

#define B_SZ 4096
#define F_SZ 24
#define V_SZ 1000
#define D_SZ 32
#define RED  8
#define FD   768      // F*D
#define COMB 1536
#define H0   1024
#define H1   512
#define EPS  1e-5f

typedef __bf16 bf16x8 __attribute__((ext_vector_type(8)));
typedef float  f32x4  __attribute__((ext_vector_type(4)));
typedef const __attribute__((address_space(1))) unsigned int* gptr_t;
typedef       __attribute__((address_space(3))) unsigned int* lptr_t;

__device__ __forceinline__ float bf2f(unsigned short u) {
    union { unsigned int i; float f; } v; v.i = ((unsigned int)u) << 16; return v.f;
}
__device__ __forceinline__ unsigned short f2bf(float f) {
    union { float f; unsigned int i; } v; v.f = f;
    unsigned int u = v.i;
    return (unsigned short)((u + 0x7FFFu + ((u >> 16) & 1u)) >> 16);
}
__device__ __forceinline__ unsigned int pack2(float a, float b) {
    return (unsigned int)f2bf(a) | ((unsigned int)f2bf(b) << 16);
}

// ---------- mega-prep: Wt reorder + w0/w1 transpose + gather/SENet + zero sums ----------
__global__ __launch_bounds__(256) void prep_gather(
        const int* __restrict__ x, const float* __restrict__ emb,
        const float* __restrict__ lint, const float* __restrict__ sw1,
        const float* __restrict__ sw2, const float* __restrict__ bw,
        const float* __restrict__ w0, const float* __restrict__ w1,
        unsigned short* __restrict__ Xbf, unsigned short* __restrict__ Wt,
        unsigned short* __restrict__ w0t, unsigned short* __restrict__ w1t,
        float* __restrict__ lin, float* __restrict__ sums) {
    int bid = blockIdx.x;
    int tid = threadIdx.x;
    if (bid < 1024) {
        int w = tid >> 6, lane = tid & 63;
        int b = bid * 4 + w;
        __shared__ int   xi[4][F_SZ];
        __shared__ float e[4][F_SZ][D_SZ];
        __shared__ float Z[4][F_SZ];
        __shared__ float r1[4][RED];
        __shared__ float Afac[4][F_SZ];
        if (lane < F_SZ) xi[w][lane] = x[b * F_SZ + lane];
        __syncthreads();
        #pragma unroll
        for (int it = 0; it < 3; it++) {
            int idx = it * 64 + lane;
            int f = idx >> 3, k4 = (idx & 7) * 4;
            float4 v = *(const float4*)&emb[((size_t)f * V_SZ + xi[w][f]) * D_SZ + k4];
            *(float4*)&e[w][f][k4] = v;
        }
        __syncthreads();
        if (lane < F_SZ) {
            float s = 0.f;
            #pragma unroll
            for (int k = 0; k < D_SZ; k++) s += e[w][lane][k];
            Z[w][lane] = s * (1.f / D_SZ);
        }
        __syncthreads();
        if (lane < RED) {
            float s = 0.f;
            #pragma unroll
            for (int f = 0; f < F_SZ; f++) s += Z[w][f] * sw1[lane * F_SZ + f];
            r1[w][lane] = fmaxf(s, 0.f);
        }
        __syncthreads();
        if (lane < F_SZ) {
            float s = 0.f;
            #pragma unroll
            for (int r = 0; r < RED; r++) s += r1[w][r] * sw2[lane * RED + r];
            Afac[w][lane] = 1.f / (1.f + expf(-s));
        }
        __syncthreads();
        #pragma unroll
        for (int it = 0; it < 3; it++) {
            int idx = it * 64 + lane;
            int f = idx >> 3, k4 = (idx & 7) * 4;
            const float* p = &e[w][f][k4];
            uint2 u, us;
            u.x = pack2(p[0], p[1]); u.y = pack2(p[2], p[3]);
            float a = Afac[w][f];
            us.x = pack2(p[0] * a, p[1] * a); us.y = pack2(p[2] * a, p[3] * a);
            *(uint2*)&Xbf[(size_t)b * FD + idx * 4] = u;
            *(uint2*)&Xbf[(size_t)(B_SZ + b) * FD + idx * 4] = us;
        }
        float lv = (lane < F_SZ) ? lint[lane * V_SZ + xi[w][lane]] : 0.f;
        #pragma unroll
        for (int off = 32; off > 0; off >>= 1) lv += __shfl_down(lv, off);
        if (lane == 0) lin[b] = lv;
    } else if (bid < 3328) {
        int o = (bid - 1024) * 256 + tid;
        int ik = o / FD, jl = o - ik * FD;
        int i = ik >> 5, k = ik & 31, j = jl >> 5, l = jl & 31;
        Wt[o] = (i == j) ? (unsigned short)0
                         : f2bf(bw[(((size_t)i * F_SZ + j) * D_SZ + k) * D_SZ + l]);
    } else if (bid < 5376) {
        __shared__ float tile[32][33];
        const float* in; unsigned short* out; int K, N, bx, by;
        if (bid < 4864) { int t = bid - 3328; in = w0; out = w0t; K = COMB; N = H0; bx = t & 31; by = t >> 5; }
        else            { int t = bid - 4864; in = w1; out = w1t; K = H0;   N = H1; bx = t & 15; by = t >> 4; }
        int tx = tid & 31, ty = tid >> 5;
        int n0 = bx * 32, k0 = by * 32;
        #pragma unroll
        for (int r = 0; r < 32; r += 8)
            tile[ty + r][tx] = in[(size_t)(k0 + ty + r) * N + n0 + tx];
        __syncthreads();
        #pragma unroll
        for (int r = 0; r < 32; r += 8)
            out[(size_t)(n0 + ty + r) * K + k0 + tx] = f2bf(tile[tx][ty + r]);
    } else {
        int o = (bid - 5376) * 256 + tid;   // 3072 floats
        sums[o] = 0.f;
    }
}

// ---------- MFMA GEMM: C = A[M,K](bf16) @ Bt[N,K]^T(bf16), TMxTN tile, BK=128 (4 subtiles) ----------
// 1-D grid, XCD-swizzled. MODE 0: C = Xbf .* S -> Obf[4096,1536]. MODE 1: +bias, bf16 store,
// fused BN stats. MODE 2: A = relu(bn(Araw)) staged via prefetched VGPRs; epilogue as MODE 1.
template<int MODE, int K, int N, int TM, int TN, int GX, int GY>
__global__ __launch_bounds__(256) void mfma_gemm(
        const unsigned short* __restrict__ A,
        const unsigned short* __restrict__ Bt,
        const float* __restrict__ bias,
        const unsigned short* __restrict__ Xbf,
        unsigned short* __restrict__ Obf,
        float* __restrict__ sum, float* __restrict__ sumsq,
        const float* __restrict__ psum, const float* __restrict__ psumsq,
        const float* __restrict__ g, const float* __restrict__ be) {
    constexpr int MI = TM / 32, NI = TN / 32;
    constexpr int NSUB = 4;                           // BK = 128 = 4 x 32-col subtiles
    constexpr int CLD = TN + 4;                       // padded fp32 C stride
    constexpr int STAGE = (TM + TN) * 256;            // bytes: 128 kcols x 2B
    constexpr int CST   = TM * CLD * 4;
    constexpr int SMEM  = STAGE > CST ? STAGE : CST;
    __shared__ __align__(16) char smem[SMEM];
    unsigned short* Abuf = (unsigned short*)smem;                   // [NSUB][TM*32]
    unsigned short* Bbuf = (unsigned short*)(smem + TM * 256);      // [NSUB][TN*32]
    float* Cst = (float*)smem;
    __shared__ float sc_s[MODE == 2 ? K : 1];
    __shared__ float sh_s[MODE == 2 ? K : 1];
    const int tid  = threadIdx.x;
    const int lane = tid & 63, wv = tid >> 6;
    const int wm = (wv >> 1) * (TM / 2), wn = (wv & 1) * (TN / 2);
    const int fr = lane & 15, kq = lane >> 4;
    const int bid = blockIdx.x;
    const int xcd = bid & 7, slot = bid >> 3;
    const int rowb = xcd * (GY / 8) + slot / GX;
    const int colb = slot % GX;
    const int bm = rowb * TM, bn = colb * TN;
    const int srow = tid >> 2;              // 0..63
    const int skc  = (tid & 3) * 8;         // 0,8,16,24 (shorts)

    if (MODE == 2) {
        #pragma unroll
        for (int q = 0; q < K / 256; q++) {
            int c = q * 256 + tid;
            float m = psum[c] * (1.f / B_SZ);
            float var = psumsq[c] * (1.f / B_SZ) - m * m;
            float rstd = rsqrtf(var + EPS);
            float sc = g[c] * rstd;
            sc_s[c] = sc;
            sh_s[c] = be[c] - m * sc;
        }
        __syncthreads();
    }

    f32x4 acc[MI][NI];
    #pragma unroll
    for (int i = 0; i < MI; i++)
        #pragma unroll
        for (int j = 0; j < NI; j++) {
            f32x4 z = {0.f, 0.f, 0.f, 0.f};
            acc[i][j] = z;
        }

    uint4 hvA[NSUB];
    if (MODE == 2) {
        #pragma unroll
        for (int s = 0; s < NSUB; s++)
            hvA[s] = *(const uint4*)&A[(size_t)(bm + srow) * K + 32 * s + skc];
    }

    for (int k0 = 0; k0 < K; k0 += 32 * NSUB) {
        if (MODE == 2) {
            #pragma unroll
            for (int s = 0; s < NSUB; s++) {
                unsigned int uu[4] = {hvA[s].x, hvA[s].y, hvA[s].z, hvA[s].w};
                unsigned int oo[4];
                #pragma unroll
                for (int q = 0; q < 4; q++) {
                    int c = k0 + 32 * s + skc + 2 * q;
                    float v0 = bf2f((unsigned short)(uu[q] & 0xFFFF)) * sc_s[c] + sh_s[c];
                    float v1 = bf2f((unsigned short)(uu[q] >> 16)) * sc_s[c + 1] + sh_s[c + 1];
                    oo[q] = pack2(fmaxf(v0, 0.f), fmaxf(v1, 0.f));
                }
                uint4 ov; ov.x = oo[0]; ov.y = oo[1]; ov.z = oo[2]; ov.w = oo[3];
                *(uint4*)&Abuf[s * TM * 32 + srow * 32 + skc] = ov;
            }
            if (k0 + 32 * NSUB < K) {   // prefetch next iteration (overlaps MFMA below)
                #pragma unroll
                for (int s = 0; s < NSUB; s++)
                    hvA[s] = *(const uint4*)&A[(size_t)(bm + srow) * K + k0 + 32 * NSUB + 32 * s + skc];
            }
        } else {
            #pragma unroll
            for (int s = 0; s < NSUB; s++)
                #pragma unroll
                for (int c = 0; c < TM / 64; c++) {
                    const unsigned short* ga = A + (size_t)(bm + c * 64 + srow) * K + k0 + 32 * s + skc;
                    char* la = smem + s * TM * 64 + c * 4096 + wv * 1024;
                    __builtin_amdgcn_global_load_lds((gptr_t)ga, (lptr_t)la, 16, 0, 0);
                }
        }
        #pragma unroll
        for (int s = 0; s < NSUB; s++)
            #pragma unroll
            for (int c = 0; c < TN / 64; c++) {
                const unsigned short* gb = Bt + (size_t)(bn + c * 64 + srow) * K + k0 + 32 * s + skc;
                char* lb = smem + TM * 256 + s * TN * 64 + c * 4096 + wv * 1024;
                __builtin_amdgcn_global_load_lds((gptr_t)gb, (lptr_t)lb, 16, 0, 0);
            }
        __syncthreads();
        #pragma unroll
        for (int s = 0; s < NSUB; s++) {
            bf16x8 af[MI], bfv[NI];
            #pragma unroll
            for (int mi = 0; mi < MI; mi++)
                af[mi] = *(const bf16x8*)&Abuf[s * TM * 32 + (wm + mi * 16 + fr) * 32 + kq * 8];
            #pragma unroll
            for (int ni = 0; ni < NI; ni++)
                bfv[ni] = *(const bf16x8*)&Bbuf[s * TN * 32 + (wn + ni * 16 + fr) * 32 + kq * 8];
            #pragma unroll
            for (int mi = 0; mi < MI; mi++)
                #pragma unroll
                for (int ni = 0; ni < NI; ni++)
                    acc[mi][ni] = __builtin_amdgcn_mfma_f32_16x16x32_bf16(
                        af[mi], bfv[ni], acc[mi][ni], 0, 0, 0);
        }
        __syncthreads();
    }

    // ---- stats (MODE 1/2) in register layout, with bias folded in ----
    if (MODE != 0) {
        #pragma unroll
        for (int ni = 0; ni < NI; ni++) {
            int col = bn + wn + ni * 16 + fr;
            float bv = bias[col];
            float s = 0.f, ss = 0.f;
            #pragma unroll
            for (int mi = 0; mi < MI; mi++)
                #pragma unroll
                for (int r = 0; r < 4; r++) {
                    float v = acc[mi][ni][r] + bv;
                    acc[mi][ni][r] = v;
                    s += v; ss += v * v;
                }
            s  += __shfl_xor(s, 16);  s  += __shfl_xor(s, 32);
            ss += __shfl_xor(ss, 16); ss += __shfl_xor(ss, 32);
            if (kq == 0) {
                atomicAdd(&sum[col], s);
                atomicAdd(&sumsq[col], ss);
            }
        }
    }

    // ---- stage fp32 C tile to LDS, then coalesced vectorized epilogue ----
    #pragma unroll
    for (int mi = 0; mi < MI; mi++)
        #pragma unroll
        for (int ni = 0; ni < NI; ni++) {
            int lrow = wm + mi * 16 + kq * 4;
            int lcol = wn + ni * 16 + fr;
            #pragma unroll
            for (int r = 0; r < 4; r++)
                Cst[(lrow + r) * CLD + lcol] = acc[mi][ni][r];
        }
    __syncthreads();
    #pragma unroll
    for (int ps = 0; ps < TM / 32; ps++) {
        int rl = ps * 32 + (tid >> 3);
        int cl = (tid & 7) * 8;
        float4 va = *(const float4*)&Cst[rl * CLD + cl];
        float4 vb = *(const float4*)&Cst[rl * CLD + cl + 4];
        float v[8] = {va.x, va.y, va.z, va.w, vb.x, vb.y, vb.z, vb.w};
        int grow = bm + rl, gcol = bn + cl;
        if (MODE == 0) {
            uint4 xv = *(const uint4*)&Xbf[(size_t)grow * FD + gcol];
            unsigned int xu[4] = {xv.x, xv.y, xv.z, xv.w};
            unsigned int oo[4];
            #pragma unroll
            for (int q = 0; q < 4; q++) {
                float x0 = bf2f((unsigned short)(xu[q] & 0xFFFF));
                float x1 = bf2f((unsigned short)(xu[q] >> 16));
                oo[q] = pack2(x0 * v[2 * q], x1 * v[2 * q + 1]);
            }
            uint4 ov; ov.x = oo[0]; ov.y = oo[1]; ov.z = oo[2]; ov.w = oo[3];
            size_t off = (grow < B_SZ)
                ? ((size_t)grow * COMB + gcol)
                : ((size_t)(grow - B_SZ) * COMB + FD + gcol);
            *(uint4*)&Obf[off] = ov;
        } else {
            unsigned int oo[4];
            #pragma unroll
            for (int q = 0; q < 4; q++)
                oo[q] = pack2(v[2 * q], v[2 * q + 1]);
            uint4 ov; ov.x = oo[0]; ov.y = oo[1]; ov.z = oo[2]; ov.w = oo[3];
            *(uint4*)&Obf[(size_t)grow * N + gcol] = ov;
        }
    }
}

// ---------- final: inline finalize1 + dot(w2) + sigmoid; 16 rows/block ----------
__global__ __launch_bounds__(256) void final_k(const unsigned short* __restrict__ h1,
        const float* __restrict__ sum, const float* __restrict__ sumsq,
        const float* __restrict__ g, const float* __restrict__ be,
        const float* __restrict__ w2, const float* __restrict__ b2,
        const float* __restrict__ lin, const float* __restrict__ bias,
        float* __restrict__ out) {
    __shared__ float sc_s[H1], sh_s[H1], w2_s[H1];
    int t = threadIdx.x;
    int wv = t >> 6, lane = t & 63;
    #pragma unroll
    for (int q = 0; q < 2; q++) {
        int c = q * 256 + t;
        float m = sum[c] * (1.f / B_SZ);
        float var = sumsq[c] * (1.f / B_SZ) - m * m;
        float rstd = rsqrtf(var + EPS);
        float sc = g[c] * rstd;
        sc_s[c] = sc;
        sh_s[c] = be[c] - m * sc;
        w2_s[c] = w2[c];
    }
    __syncthreads();
    int r0 = blockIdx.x * 16;
    #pragma unroll
    for (int i = 0; i < 4; i++) {
        int row = r0 + wv * 4 + i;
        int c0 = lane * 8;
        uint4 hv = *(const uint4*)&h1[(size_t)row * H1 + c0];
        unsigned int uu[4] = {hv.x, hv.y, hv.z, hv.w};
        float acc = 0.f;
        #pragma unroll
        for (int q = 0; q < 4; q++) {
            int c = c0 + 2 * q;
            float v0 = bf2f((unsigned short)(uu[q] & 0xFFFF)) * sc_s[c] + sh_s[c];
            float v1 = bf2f((unsigned short)(uu[q] >> 16)) * sc_s[c + 1] + sh_s[c + 1];
            acc += fmaxf(v0, 0.f) * w2_s[c] + fmaxf(v1, 0.f) * w2_s[c + 1];
        }
        #pragma unroll
        for (int off = 32; off > 0; off >>= 1) acc += __shfl_down(acc, off);
        if (lane == 0) {
            float logit = lin[row] + bias[0] + acc + b2[0];
            out[row] = 1.f / (1.f + expf(-logit));
        }
    }
}

extern "C" void kernel_launch(void* const* d_in, const int* in_sizes, int n_in,
                              void* d_out, int out_size, void* d_ws, size_t ws_size,
                              hipStream_t stream) {
    const int*   x    = (const int*)d_in[0];
    const float* emb  = (const float*)d_in[1];
    const float* lint = (const float*)d_in[2];
    const float* bias = (const float*)d_in[3];
    const float* sw1  = (const float*)d_in[4];
    const float* sw2  = (const float*)d_in[5];
    const float* bw   = (const float*)d_in[6];
    const float* w0   = (const float*)d_in[7];
    const float* b0   = (const float*)d_in[8];
    const float* g0   = (const float*)d_in[9];
    const float* be0  = (const float*)d_in[10];
    const float* w1   = (const float*)d_in[11];
    const float* b1   = (const float*)d_in[12];
    const float* g1   = (const float*)d_in[13];
    const float* be1  = (const float*)d_in[14];
    const float* w2   = (const float*)d_in[15];
    const float* b2   = (const float*)d_in[16];
    float* out = (float*)d_out;

    char* p = (char*)d_ws;
    auto alloc = [&](size_t bytes) { char* r = p; p += (bytes + 255) & ~(size_t)255; return r; };

    unsigned short* Xbf  = (unsigned short*)alloc((size_t)2 * B_SZ * FD * 2);
    unsigned short* Wt   = (unsigned short*)alloc((size_t)FD * FD * 2);
    unsigned short* w0t  = (unsigned short*)alloc((size_t)H0 * COMB * 2);
    unsigned short* w1t  = (unsigned short*)alloc((size_t)H1 * H0 * 2);
    unsigned short* Cbf  = (unsigned short*)alloc((size_t)B_SZ * COMB * 2);
    unsigned short* h0bf = (unsigned short*)alloc((size_t)B_SZ * H0 * 2);
    unsigned short* h1bf = (unsigned short*)alloc((size_t)B_SZ * H1 * 2);
    float* lin = (float*)alloc(B_SZ * 4);
    float* sums = (float*)alloc((2 * H0 + 2 * H1) * 4);
    float* sum0 = sums, *sumsq0 = sums + H0, *sum1 = sums + 2 * H0, *sumsq1 = sums + 2 * H0 + H1;

    prep_gather<<<5388, 256, 0, stream>>>(x, emb, lint, sw1, sw2, bw, w0, w1,
                                          Xbf, Wt, w0t, w1t, lin, sums);

    // S = X @ Wt^T, epilogue: Cbf = bf16(X .* S)   [768 blocks, XCD-swizzled, 3/CU]
    mfma_gemm<0, FD, FD, 128, 64, 12, 64><<<768, 256, 0, stream>>>(
        Xbf, Wt, nullptr, Xbf, Cbf, nullptr, nullptr, nullptr, nullptr, nullptr, nullptr);
    // h0 = Cbf @ w0 + b0 (+stats)   [512 blocks, 2/CU]
    mfma_gemm<1, COMB, H0, 128, 64, 16, 32><<<512, 256, 0, stream>>>(
        Cbf, w0t, b0, nullptr, h0bf, sum0, sumsq0, nullptr, nullptr, nullptr, nullptr);
    // h1 = relu(bn(h0)) @ w1 + b1 (+stats), BN0 finalize+apply fused into A-staging
    mfma_gemm<2, H0, H1, 64, 64, 8, 64><<<512, 256, 0, stream>>>(
        h0bf, w1t, b1, nullptr, h1bf, sum1, sumsq1, sum0, sumsq0, g0, be0);
    // BN1 finalize + dot + sigmoid fused
    final_k<<<B_SZ / 16, 256, 0, stream>>>(h1bf, sum1, sumsq1, g1, be1,
                                           w2, b2, lin, bias, out);
}